// Round 1
// baseline (651.636 us; speedup 1.0000x reference)
//
#include <hip/hip_runtime.h>

#define NODES 1430
#define GENE0 1421
#define NHEADS 9

__device__ __forceinline__ float frelu(float v) { return v > 0.f ? v : 0.f; }

// Pass A: degree count (float atomic, exact for small ints) + compact gene-dst
// edges into a list, flag their src nodes as "layer-1 result needed".
__global__ void k_deg_compact(const int* __restrict__ esrc, const int* __restrict__ edst,
                              float* __restrict__ deg, unsigned char* __restrict__ flag,
                              int2* __restrict__ list, int* __restrict__ counter,
                              int e, int cap) {
    int j = blockIdx.x * blockDim.x + threadIdx.x;
    if (j >= e) return;
    int d = edst[j];
    atomicAdd(deg + d, 1.0f);
    int graph = d / NODES;
    int pos = d - graph * NODES;
    if (pos >= GENE0) {                 // edge feeds a gene node (~0.63%)
        int s = esrc[j];
        flag[s] = 1;                    // benign write race (same value)
        int p = atomicAdd(counter, 1);
        if (p < cap) list[p] = make_int2(s, d);
    }
}

// Pass B: dinv = rsqrt(deg+1) in place; also flag the gene nodes themselves
// (their layer-1 value is needed for the layer-2 self-loop term).
__global__ void k_dinv(float* __restrict__ deg, unsigned char* __restrict__ flag, int n) {
    int i = blockIdx.x * blockDim.x + threadIdx.x;
    if (i >= n) return;
    deg[i] = rsqrtf(deg[i] + 1.0f);
    int graph = i / NODES;
    int pos = i - graph * NODES;
    if (pos >= GENE0) flag[i] = 1;
}

// Pass C: scalar layer-1 scatter, but only into flagged dst nodes
// t[d] += dinv[s]*dinv[d]*x[s]   (u[d] = t[d] + dinv[d]^2 * x[d], done on the fly later)
__global__ void k_l1_scatter(const int* __restrict__ esrc, const int* __restrict__ edst,
                             const float* __restrict__ x, const float* __restrict__ dinv,
                             const unsigned char* __restrict__ flag,
                             float* __restrict__ t, int e) {
    int j = blockIdx.x * blockDim.x + threadIdx.x;
    if (j >= e) return;
    int d = edst[j];
    if (!flag[d]) return;               // ~99.3% of lanes exit here
    int s = esrc[j];
    atomicAdd(t + d, dinv[s] * dinv[d] * x[s]);
}

// Pass D: for each compacted gene edge, rebuild h2[src] from the scalar u[src]
// (relu(u*W1+b1) @ W2) and scatter norm*h2 into the per-gene accumulator.
__global__ void k_gene_edges(const int2* __restrict__ list, const int* __restrict__ counter,
                             const float* __restrict__ t, const float* __restrict__ dinv,
                             const float* __restrict__ x,
                             const float* __restrict__ W1, const float* __restrict__ b1,
                             const float* __restrict__ W2,
                             float* __restrict__ agg, int cap) {
    int j = blockIdx.x * blockDim.x + threadIdx.x;
    int cnt = *counter;
    if (cnt > cap) cnt = cap;
    if (j >= cnt) return;
    int2 sd = list[j];
    int s = sd.x, d = sd.y;
    float ds = dinv[s];
    float us = t[s] + ds * ds * x[s];   // layer-1 pre-W1 scalar at src
    float l1[16];
#pragma unroll
    for (int k = 0; k < 16; k++) l1[k] = frelu(us * W1[k] + b1[k]);
    int graph = d / NODES;
    int head = d - graph * NODES - GENE0;
    float* ag = agg + (size_t)(graph * NHEADS + head) * 16;
    float norm = ds * dinv[d];
#pragma unroll
    for (int c = 0; c < 16; c++) {
        float h2 = 0.f;
#pragma unroll
        for (int k = 0; k < 16; k++) h2 += l1[k] * W2[k * 16 + c];
        atomicAdd(ag + c, norm * h2);
    }
}

// Pass E: finalize gene nodes (self-loop + bias + relu) and run the per-head
// 16->8->1 MLP; write outputs in tuple order out[head*G + graph].
__global__ void k_final(const float* __restrict__ t, const float* __restrict__ dinv,
                        const float* __restrict__ x,
                        const float* __restrict__ W1, const float* __restrict__ b1,
                        const float* __restrict__ W2, const float* __restrict__ b2,
                        const float* __restrict__ fw1, const float* __restrict__ fb1,
                        const float* __restrict__ fw2, const float* __restrict__ fb2,
                        const float* __restrict__ agg, float* __restrict__ out, int G) {
    int gid = blockIdx.x * blockDim.x + threadIdx.x;
    if (gid >= G * NHEADS) return;
    int graph = gid / NHEADS;
    int head = gid - graph * NHEADS;
    int node = graph * NODES + GENE0 + head;
    float dn = dinv[node];
    float un = t[node] + dn * dn * x[node];
    float l1[16];
#pragma unroll
    for (int k = 0; k < 16; k++) l1[k] = frelu(un * W1[k] + b1[k]);
    float dsq = dn * dn;
    float h[16];
#pragma unroll
    for (int c = 0; c < 16; c++) {
        float h2 = 0.f;
#pragma unroll
        for (int k = 0; k < 16; k++) h2 += l1[k] * W2[k * 16 + c];
        h[c] = frelu(agg[(size_t)gid * 16 + c] + dsq * h2 + b2[c]);
    }
    float pred = fb2[head];
#pragma unroll
    for (int kk = 0; kk < 8; kk++) {
        float z = fb1[head * 8 + kk];
#pragma unroll
        for (int c = 0; c < 16; c++) z += h[c] * fw1[head * 128 + c * 8 + kk];
        pred += frelu(z) * fw2[head * 8 + kk];
    }
    out[head * G + graph] = pred;
}

extern "C" void kernel_launch(void* const* d_in, const int* in_sizes, int n_in,
                              void* d_out, int out_size, void* d_ws, size_t ws_size,
                              hipStream_t stream) {
    const float* x   = (const float*)d_in[0];
    const int*   ei  = (const int*)d_in[1];
    const float* W1  = (const float*)d_in[3];
    const float* b1  = (const float*)d_in[4];
    const float* W2  = (const float*)d_in[5];
    const float* b2  = (const float*)d_in[6];
    const float* fw1 = (const float*)d_in[7];
    const float* fb1 = (const float*)d_in[8];
    const float* fw2 = (const float*)d_in[9];
    const float* fb2 = (const float*)d_in[10];

    int n = in_sizes[0];
    int e = in_sizes[1] / 2;
    int G = in_sizes[2] / NHEADS;
    const int* esrc = ei;
    const int* edst = ei + e;

    char* ws = (char*)d_ws;
    size_t off = 0;
    auto alloc = [&](size_t bytes) {
        char* p = ws + off;
        off += (bytes + 255) & ~(size_t)255;
        return p;
    };
    float* deg          = (float*)alloc((size_t)n * 4);              // becomes dinv in place
    float* t            = (float*)alloc((size_t)n * 4);
    float* agg          = (float*)alloc((size_t)G * NHEADS * 16 * 4);
    int*   counter      = (int*)alloc(4);
    unsigned char* flag = (unsigned char*)alloc((size_t)n);
    size_t zero_bytes   = off;                                       // all of the above need zeroing
    int cap = e / 64 + 4096;                                         // expected hits ~E*9/1430, huge margin
    int2* list          = (int2*)alloc((size_t)cap * 8);
    (void)ws_size; (void)n_in; (void)out_size; (void)list;

    hipMemsetAsync(d_ws, 0, zero_bytes, stream);

    const int B = 256;
    int gridE = (e + B - 1) / B;
    int gridN = (n + B - 1) / B;

    k_deg_compact<<<gridE, B, 0, stream>>>(esrc, edst, deg, flag, list, counter, e, cap);
    k_dinv<<<gridN, B, 0, stream>>>(deg, flag, n);
    k_l1_scatter<<<gridE, B, 0, stream>>>(esrc, edst, x, deg, flag, t, e);
    k_gene_edges<<<(cap + B - 1) / B, B, 0, stream>>>(list, counter, t, deg, x, W1, b1, W2, agg, cap);
    k_final<<<(G * NHEADS + B - 1) / B, B, 0, stream>>>(t, deg, x, W1, b1, W2, b2,
                                                        fw1, fb1, fw2, fb2, agg,
                                                        (float*)d_out, G);
}

// Round 2
// 454.506 us; speedup vs baseline: 1.4337x; 1.4337x over previous
//
#include <hip/hip_runtime.h>

#define NODES 1430
#define GENE0 1421
#define NHEADS 9
#define BINS 65536            // nodes per range; u8 counts packed 4-per-u32
#define LDSW (BINS / 4)       // 16384 u32 words = 64 KB LDS
#define GMAX 64               // max bucketed in-edges per gene (Poisson(8) tail ~0)

__device__ __forceinline__ float frelu(float v) { return v > 0.f ? v : 0.f; }

// Pass 1: privatized LDS histogram of in-degree (range r of node space, chunk k
// of edge space). r==0 blocks additionally detect gene-dst edges, bucket their
// src per gene, and flag srcs for the layer-1 scatter.
__global__ void k_hist(const int* __restrict__ esrc, const int* __restrict__ edst,
                       unsigned int* __restrict__ copies,      // [K][R*LDSW] u32
                       int* __restrict__ gene_cnt, int* __restrict__ gene_src,
                       unsigned char* __restrict__ flag,
                       int e, int K, int R) {
    extern __shared__ unsigned int lds[];
    const int k = blockIdx.x, r = blockIdx.y;
    const int tid = threadIdx.x;
    for (int w = tid; w < LDSW; w += blockDim.x) lds[w] = 0u;
    __syncthreads();

    const unsigned int lo = (unsigned int)r * BINS;
    const int e4 = e >> 2;
    const int Q = (e4 + K - 1) / K;
    const int beg = k * Q;
    const int end = min(beg + Q, e4);
    const int4* ed4 = (const int4*)edst;

    for (int j = beg + tid; j < end; j += blockDim.x) {
        int4 d4 = ed4[j];
#pragma unroll
        for (int c = 0; c < 4; c++) {
            unsigned int d = (unsigned int)((&d4.x)[c]);
            unsigned int rel = d - lo;
            if (rel < BINS)
                atomicAdd(&lds[rel >> 2], 1u << ((rel & 3u) * 8u));
            if (r == 0) {
                unsigned int graph = d / NODES;
                unsigned int pos = d - graph * NODES;
                if (pos >= GENE0) {
                    int s = esrc[4 * j + c];
                    flag[s] = 1;
                    int g = (int)(graph * NHEADS + (pos - GENE0));
                    int p = atomicAdd(gene_cnt + g, 1);
                    if (p < GMAX) gene_src[(g << 6) + p] = s;
                }
            }
        }
    }
    // tail edges (e % 4) — handled by chunk-0 blocks (every range must test)
    if (k == 0) {
        for (int j = (e4 << 2) + tid; j < e; j += blockDim.x) {
            unsigned int d = (unsigned int)edst[j];
            unsigned int rel = d - lo;
            if (rel < BINS)
                atomicAdd(&lds[rel >> 2], 1u << ((rel & 3u) * 8u));
            if (r == 0) {
                unsigned int graph = d / NODES;
                unsigned int pos = d - graph * NODES;
                if (pos >= GENE0) {
                    int s = esrc[j];
                    flag[s] = 1;
                    int g = (int)(graph * NHEADS + (pos - GENE0));
                    int p = atomicAdd(gene_cnt + g, 1);
                    if (p < GMAX) gene_src[(g << 6) + p] = s;
                }
            }
        }
    }
    __syncthreads();
    unsigned int* dst = copies + ((size_t)k * R + r) * LDSW;
    for (int w = tid; w < LDSW; w += blockDim.x) dst[w] = lds[w];
}

// Pass 2: sum the K histogram copies, dinv = rsqrt(deg+1), flag gene nodes.
__global__ void k_reduce(const unsigned int* __restrict__ copies,
                         float* __restrict__ dinv, unsigned char* __restrict__ flag,
                         int n, int K, int R) {
    int w = blockIdx.x * blockDim.x + threadIdx.x;
    int Wtot = R * LDSW;
    if (w >= Wtot) return;
    unsigned int c0 = 0, c1 = 0, c2 = 0, c3 = 0;
    for (int k = 0; k < K; k++) {
        unsigned int u = copies[(size_t)k * Wtot + w];
        c0 += u & 0xffu; c1 += (u >> 8) & 0xffu;
        c2 += (u >> 16) & 0xffu; c3 += u >> 24;
    }
    int i0 = w << 2;
    float4 dv;
    dv.x = rsqrtf((float)c0 + 1.f);
    dv.y = rsqrtf((float)c1 + 1.f);
    dv.z = rsqrtf((float)c2 + 1.f);
    dv.w = rsqrtf((float)c3 + 1.f);
    if (i0 + 3 < n) {
        *(float4*)(dinv + i0) = dv;
    } else {
        float v[4] = {dv.x, dv.y, dv.z, dv.w};
        for (int b = 0; b < 4; b++) if (i0 + b < n) dinv[i0 + b] = v[b];
    }
#pragma unroll
    for (int b = 0; b < 4; b++) {
        int i = i0 + b;
        if (i < n) {
            unsigned int graph = (unsigned int)i / NODES;
            unsigned int pos = (unsigned int)i - graph * NODES;
            if (pos >= GENE0) flag[i] = 1;
        }
    }
}

// Pass 3: scalar layer-1 scatter into flagged nodes only (~5.6% of edges).
__global__ void k_l1_scatter(const int* __restrict__ esrc, const int* __restrict__ edst,
                             const float* __restrict__ x, const float* __restrict__ dinv,
                             const unsigned char* __restrict__ flag,
                             float* __restrict__ t, int e) {
    int j = blockIdx.x * blockDim.x + threadIdx.x;
    if (j >= e) return;
    int d = edst[j];
    if (!flag[d]) return;
    int s = esrc[j];
    atomicAdd(t + d, dinv[s] * dinv[d] * x[s]);
}

// Pass 4: per-gene gather over its bucketed in-edges; rebuild h2[src] on the
// fly from the scalar layer-1 value; non-atomic store of the aggregate.
__global__ void k_gene(const int* __restrict__ gene_cnt, const int* __restrict__ gene_src,
                       const float* __restrict__ t, const float* __restrict__ dinv,
                       const float* __restrict__ x,
                       const float* __restrict__ W1, const float* __restrict__ b1,
                       const float* __restrict__ W2,
                       float* __restrict__ agg, int NG) {
    int g = blockIdx.x * blockDim.x + threadIdx.x;
    if (g >= NG) return;
    int graph = g / NHEADS;
    int head = g - graph * NHEADS;
    int node = graph * NODES + GENE0 + head;
    float dd = dinv[node];
    int cnt = min(gene_cnt[g], GMAX);
    float acc[16];
#pragma unroll
    for (int c = 0; c < 16; c++) acc[c] = 0.f;
    for (int i = 0; i < cnt; i++) {
        int s = gene_src[(g << 6) + i];
        float ds = dinv[s];
        float us = t[s] + ds * ds * x[s];
        float l1[16];
#pragma unroll
        for (int kk = 0; kk < 16; kk++) l1[kk] = frelu(us * W1[kk] + b1[kk]);
#pragma unroll
        for (int c = 0; c < 16; c++) {
            float m = 0.f;
#pragma unroll
            for (int kk = 0; kk < 16; kk++) m += l1[kk] * W2[kk * 16 + c];
            acc[c] += ds * m;
        }
    }
    float* ag = agg + (size_t)g * 16;
#pragma unroll
    for (int c = 0; c < 16; c++) ag[c] = dd * acc[c];
}

// Pass 5: finalize gene nodes (self-loop + bias + relu) + per-head 16->8->1 MLP.
__global__ void k_final(const float* __restrict__ t, const float* __restrict__ dinv,
                        const float* __restrict__ x,
                        const float* __restrict__ W1, const float* __restrict__ b1,
                        const float* __restrict__ W2, const float* __restrict__ b2,
                        const float* __restrict__ fw1, const float* __restrict__ fb1,
                        const float* __restrict__ fw2, const float* __restrict__ fb2,
                        const float* __restrict__ agg, float* __restrict__ out, int G) {
    int gid = blockIdx.x * blockDim.x + threadIdx.x;
    if (gid >= G * NHEADS) return;
    int graph = gid / NHEADS;
    int head = gid - graph * NHEADS;
    int node = graph * NODES + GENE0 + head;
    float dn = dinv[node];
    float un = t[node] + dn * dn * x[node];
    float l1[16];
#pragma unroll
    for (int k = 0; k < 16; k++) l1[k] = frelu(un * W1[k] + b1[k]);
    float dsq = dn * dn;
    float h[16];
#pragma unroll
    for (int c = 0; c < 16; c++) {
        float h2 = 0.f;
#pragma unroll
        for (int k = 0; k < 16; k++) h2 += l1[k] * W2[k * 16 + c];
        h[c] = frelu(agg[(size_t)gid * 16 + c] + dsq * h2 + b2[c]);
    }
    float pred = fb2[head];
#pragma unroll
    for (int kk = 0; kk < 8; kk++) {
        float z = fb1[head * 8 + kk];
#pragma unroll
        for (int c = 0; c < 16; c++) z += h[c] * fw1[head * 128 + c * 8 + kk];
        pred += frelu(z) * fw2[head * 8 + kk];
    }
    out[head * G + graph] = pred;
}

extern "C" void kernel_launch(void* const* d_in, const int* in_sizes, int n_in,
                              void* d_out, int out_size, void* d_ws, size_t ws_size,
                              hipStream_t stream) {
    const float* x   = (const float*)d_in[0];
    const int*   ei  = (const int*)d_in[1];
    const float* W1  = (const float*)d_in[3];
    const float* b1  = (const float*)d_in[4];
    const float* W2  = (const float*)d_in[5];
    const float* b2  = (const float*)d_in[6];
    const float* fw1 = (const float*)d_in[7];
    const float* fb1 = (const float*)d_in[8];
    const float* fw2 = (const float*)d_in[9];
    const float* fb2 = (const float*)d_in[10];

    int n = in_sizes[0];
    int e = in_sizes[1] / 2;
    int G = in_sizes[2] / NHEADS;
    int NG = G * NHEADS;
    const int* esrc = ei;
    const int* edst = ei + e;

    char* ws = (char*)d_ws;
    size_t off = 0;
    auto alloc = [&](size_t bytes) {
        char* p = ws + off;
        off += (bytes + 255) & ~(size_t)255;
        return p;
    };
    // zero-init region first
    float* t             = (float*)alloc((size_t)n * 4);
    int*   gene_cnt      = (int*)alloc((size_t)NG * 4);
    unsigned char* flag  = (unsigned char*)alloc((size_t)n);
    size_t zero_bytes    = off;
    // written-before-read region
    float* dinv          = (float*)alloc((size_t)n * 4);
    float* agg           = (float*)alloc((size_t)NG * 16 * 4);
    int*   gene_src      = (int*)alloc((size_t)NG * GMAX * 4);
    size_t fixed         = off;

    int R = (n + BINS - 1) / BINS;                    // node ranges (12 for n=732160)
    size_t per_copy = (size_t)R * LDSW * 4;           // one chunk's histogram slab
    int K = 42;                                       // edge chunks -> 504 blocks, 2/CU
    if (fixed + (size_t)K * per_copy > ws_size) {
        size_t avail = (ws_size > fixed) ? (ws_size - fixed) : 0;
        int kfit = (int)(avail / per_copy);
        K = kfit < 1 ? 1 : (kfit < K ? kfit : K);
    }
    unsigned int* copies = (unsigned int*)alloc((size_t)K * per_copy);
    (void)n_in; (void)out_size; (void)ws_size;

    hipMemsetAsync(d_ws, 0, zero_bytes, stream);

    const int B = 256;
    k_hist<<<dim3(K, R), B, BINS, stream>>>(esrc, edst, copies, gene_cnt, gene_src,
                                            flag, e, K, R);
    int Wtot = R * LDSW;
    k_reduce<<<(Wtot + B - 1) / B, B, 0, stream>>>(copies, dinv, flag, n, K, R);
    k_l1_scatter<<<(e + B - 1) / B, B, 0, stream>>>(esrc, edst, x, dinv, flag, t, e);
    k_gene<<<(NG + B - 1) / B, B, 0, stream>>>(gene_cnt, gene_src, t, dinv, x,
                                               W1, b1, W2, agg, NG);
    k_final<<<(NG + B - 1) / B, B, 0, stream>>>(t, dinv, x, W1, b1, W2, b2,
                                                fw1, fb1, fw2, fb2, agg,
                                                (float*)d_out, G);
}

// Round 3
// 364.748 us; speedup vs baseline: 1.7865x; 1.2461x over previous
//
#include <hip/hip_runtime.h>

#define NODES 1430
#define GENE0 1421
#define NHEADS 9
#define HBINS 65536          // bins per block; 4-bit counts, 8 per u32
#define HWORDS (HBINS / 8)   // 8192 u32 words = 32 KB LDS -> 5 blocks/CU
#define GMAX 64              // max bucketed in-edges per gene (Poisson(8) tail ~0)

__device__ __forceinline__ float frelu(float v) { return v > 0.f ? v : 0.f; }

// Pass 1: privatized LDS histogram (4-bit packed) of in-degree.
// Grid (K chunks, R ranges). r==0 blocks also bucket gene-dst edges.
__global__ void k_hist(const int* __restrict__ esrc, const int* __restrict__ edst,
                       unsigned int* __restrict__ copies,      // [K][R*HWORDS]
                       int* __restrict__ gene_cnt, int* __restrict__ gene_src,
                       unsigned char* __restrict__ flag,
                       int e, int K, int R) {
    __shared__ unsigned int lds[HWORDS];
    const int k = blockIdx.x, r = blockIdx.y;
    const int tid = threadIdx.x;
    {
        uint4* l4 = (uint4*)lds;
        for (int w = tid; w < HWORDS / 4; w += 256) l4[w] = make_uint4(0, 0, 0, 0);
    }
    __syncthreads();

    const unsigned int lo = (unsigned int)r * HBINS;
    const int e4 = e >> 2;
    const int Q = (e4 + K - 1) / K;
    const int beg = k * Q;
    const int end = min(beg + Q, e4);
    const int4* ed4 = (const int4*)edst;
    const int len = (end > beg) ? (end - beg) : 0;
    const int half = len >> 1;

    auto proc = [&](int j, int4 d4) {
#pragma unroll
        for (int c = 0; c < 4; c++) {
            unsigned int d = (unsigned int)((&d4.x)[c]);
            unsigned int rel = d - lo;
            if (rel < HBINS)
                atomicAdd(&lds[rel >> 3], 1u << ((rel & 7u) * 4u));
            if (r == 0) {
                unsigned int graph = d / NODES;
                unsigned int pos = d - graph * NODES;
                if (pos >= GENE0) {
                    int s = esrc[4 * j + c];
                    flag[s] = 1;
                    int g = (int)(graph * NHEADS + (pos - GENE0));
                    int p = atomicAdd(gene_cnt + g, 1);
                    if (p < GMAX) gene_src[(g << 6) + p] = s;
                }
            }
        }
    };

    // two independent streams -> 2 loads in flight per wave
    for (int i = tid; i < half; i += 256) {
        int j1 = beg + i, j2 = beg + i + half;
        int4 a = ed4[j1];
        int4 b = ed4[j2];
        proc(j1, a);
        proc(j2, b);
    }
    if ((len & 1) && tid == 0) {
        int j = beg + len - 1;
        proc(j, ed4[j]);
    }
    // tail edges (e % 4) — chunk-0 blocks of every range
    if (k == 0) {
        for (int j = (e4 << 2) + tid; j < e; j += 256) {
            unsigned int d = (unsigned int)edst[j];
            unsigned int rel = d - lo;
            if (rel < HBINS)
                atomicAdd(&lds[rel >> 3], 1u << ((rel & 7u) * 4u));
            if (r == 0) {
                unsigned int graph = d / NODES;
                unsigned int pos = d - graph * NODES;
                if (pos >= GENE0) {
                    int s = esrc[j];
                    flag[s] = 1;
                    int g = (int)(graph * NHEADS + (pos - GENE0));
                    int p = atomicAdd(gene_cnt + g, 1);
                    if (p < GMAX) gene_src[(g << 6) + p] = s;
                }
            }
        }
    }
    __syncthreads();
    uint4* dst4 = (uint4*)(copies + ((size_t)k * R + r) * HWORDS);
    const uint4* l4 = (const uint4*)lds;
    for (int w = tid; w < HWORDS / 4; w += 256) dst4[w] = l4[w];
}

// Pass 2: sum K nibble-histograms (SWAR even/odd), dinv = rsqrt(deg+1),
// flag gene nodes. Each thread owns one word = 8 consecutive nodes.
__global__ void k_reduce(const unsigned int* __restrict__ copies,
                         float* __restrict__ dinv, unsigned char* __restrict__ flag,
                         int n, int K, int Wtot) {
    int w = blockIdx.x * blockDim.x + threadIdx.x;
    if (w >= Wtot) return;
    unsigned int evn = 0, odd = 0;
    for (int k = 0; k < K; k++) {
        unsigned int u = copies[(size_t)k * Wtot + w];
        evn += u & 0x0F0F0F0Fu;
        odd += (u >> 4) & 0x0F0F0F0Fu;
    }
    int i0 = w << 3;
    float v[8];
#pragma unroll
    for (int b = 0; b < 4; b++) {
        v[2 * b]     = (float)((evn >> (8 * b)) & 0xFFu);
        v[2 * b + 1] = (float)((odd >> (8 * b)) & 0xFFu);
    }
#pragma unroll
    for (int b = 0; b < 8; b++) v[b] = rsqrtf(v[b] + 1.f);
    if (i0 + 7 < n) {
        float4 lo4 = {v[0], v[1], v[2], v[3]};
        float4 hi4 = {v[4], v[5], v[6], v[7]};
        *(float4*)(dinv + i0) = lo4;
        *(float4*)(dinv + i0 + 4) = hi4;
    } else {
        for (int b = 0; b < 8; b++) if (i0 + b < n) dinv[i0 + b] = v[b];
    }
#pragma unroll
    for (int b = 0; b < 8; b++) {
        int i = i0 + b;
        if (i < n) {
            unsigned int graph = (unsigned int)i / NODES;
            unsigned int pos = (unsigned int)i - graph * NODES;
            if (pos >= GENE0) flag[i] = 1;
        }
    }
}

// Pass 3: scalar layer-1 scatter into flagged dst only (~5.6% of edges),
// vectorized dst read (4 edges/thread).
__global__ void k_l1_scatter(const int* __restrict__ esrc, const int* __restrict__ edst,
                             const float* __restrict__ x, const float* __restrict__ dinv,
                             const unsigned char* __restrict__ flag,
                             float* __restrict__ t, int e) {
    int q = blockIdx.x * blockDim.x + threadIdx.x;
    int e4 = e >> 2;
    if (q < e4) {
        int4 d4 = ((const int4*)edst)[q];
#pragma unroll
        for (int c = 0; c < 4; c++) {
            int d = (&d4.x)[c];
            if (!flag[d]) continue;
            int s = esrc[4 * q + c];
            atomicAdd(t + d, dinv[s] * dinv[d] * x[s]);
        }
    } else if (q == e4) {
        for (int j = e4 << 2; j < e; j++) {
            int d = edst[j];
            if (!flag[d]) continue;
            int s = esrc[j];
            atomicAdd(t + d, dinv[s] * dinv[d] * x[s]);
        }
    }
}

// Pass 4: per-gene gather over bucketed in-edges; rebuild h2[src] on the fly.
__global__ void k_gene(const int* __restrict__ gene_cnt, const int* __restrict__ gene_src,
                       const float* __restrict__ t, const float* __restrict__ dinv,
                       const float* __restrict__ x,
                       const float* __restrict__ W1, const float* __restrict__ b1,
                       const float* __restrict__ W2,
                       float* __restrict__ agg, int NG) {
    int g = blockIdx.x * blockDim.x + threadIdx.x;
    if (g >= NG) return;
    int graph = g / NHEADS;
    int head = g - graph * NHEADS;
    int node = graph * NODES + GENE0 + head;
    float dd = dinv[node];
    int cnt = min(gene_cnt[g], GMAX);
    float acc[16];
#pragma unroll
    for (int c = 0; c < 16; c++) acc[c] = 0.f;
    for (int i = 0; i < cnt; i++) {
        int s = gene_src[(g << 6) + i];
        float ds = dinv[s];
        float us = t[s] + ds * ds * x[s];
        float l1[16];
#pragma unroll
        for (int kk = 0; kk < 16; kk++) l1[kk] = frelu(us * W1[kk] + b1[kk]);
#pragma unroll
        for (int c = 0; c < 16; c++) {
            float m = 0.f;
#pragma unroll
            for (int kk = 0; kk < 16; kk++) m += l1[kk] * W2[kk * 16 + c];
            acc[c] += ds * m;
        }
    }
    float* ag = agg + (size_t)g * 16;
#pragma unroll
    for (int c = 0; c < 16; c++) ag[c] = dd * acc[c];
}

// Pass 5: finalize gene nodes + per-head 16->8->1 MLP.
__global__ void k_final(const float* __restrict__ t, const float* __restrict__ dinv,
                        const float* __restrict__ x,
                        const float* __restrict__ W1, const float* __restrict__ b1,
                        const float* __restrict__ W2, const float* __restrict__ b2,
                        const float* __restrict__ fw1, const float* __restrict__ fb1,
                        const float* __restrict__ fw2, const float* __restrict__ fb2,
                        const float* __restrict__ agg, float* __restrict__ out, int G) {
    int gid = blockIdx.x * blockDim.x + threadIdx.x;
    if (gid >= G * NHEADS) return;
    int graph = gid / NHEADS;
    int head = gid - graph * NHEADS;
    int node = graph * NODES + GENE0 + head;
    float dn = dinv[node];
    float un = t[node] + dn * dn * x[node];
    float l1[16];
#pragma unroll
    for (int k = 0; k < 16; k++) l1[k] = frelu(un * W1[k] + b1[k]);
    float dsq = dn * dn;
    float h[16];
#pragma unroll
    for (int c = 0; c < 16; c++) {
        float h2 = 0.f;
#pragma unroll
        for (int k = 0; k < 16; k++) h2 += l1[k] * W2[k * 16 + c];
        h[c] = frelu(agg[(size_t)gid * 16 + c] + dsq * h2 + b2[c]);
    }
    float pred = fb2[head];
#pragma unroll
    for (int kk = 0; kk < 8; kk++) {
        float z = fb1[head * 8 + kk];
#pragma unroll
        for (int c = 0; c < 16; c++) z += h[c] * fw1[head * 128 + c * 8 + kk];
        pred += frelu(z) * fw2[head * 8 + kk];
    }
    out[head * G + graph] = pred;
}

extern "C" void kernel_launch(void* const* d_in, const int* in_sizes, int n_in,
                              void* d_out, int out_size, void* d_ws, size_t ws_size,
                              hipStream_t stream) {
    const float* x   = (const float*)d_in[0];
    const int*   ei  = (const int*)d_in[1];
    const float* W1  = (const float*)d_in[3];
    const float* b1  = (const float*)d_in[4];
    const float* W2  = (const float*)d_in[5];
    const float* b2  = (const float*)d_in[6];
    const float* fw1 = (const float*)d_in[7];
    const float* fb1 = (const float*)d_in[8];
    const float* fw2 = (const float*)d_in[9];
    const float* fb2 = (const float*)d_in[10];

    int n = in_sizes[0];
    int e = in_sizes[1] / 2;
    int G = in_sizes[2] / NHEADS;
    int NG = G * NHEADS;
    const int* esrc = ei;
    const int* edst = ei + e;

    char* ws = (char*)d_ws;
    size_t off = 0;
    auto alloc = [&](size_t bytes) {
        char* p = ws + off;
        off += (bytes + 255) & ~(size_t)255;
        return p;
    };
    // zero-init region first
    float* t             = (float*)alloc((size_t)n * 4);
    int*   gene_cnt      = (int*)alloc((size_t)NG * 4);
    unsigned char* flag  = (unsigned char*)alloc((size_t)n);
    size_t zero_bytes    = off;
    // written-before-read region
    float* dinv          = (float*)alloc((size_t)n * 4);
    float* agg           = (float*)alloc((size_t)NG * 16 * 4);
    int*   gene_src      = (int*)alloc((size_t)NG * GMAX * 4);
    size_t fixed         = off;

    int R = (n + HBINS - 1) / HBINS;                  // 12 for n=732160
    size_t per_copy = (size_t)R * HWORDS * 4;         // 384 KB per chunk
    int K = 106;                                      // K*R = 1272 blocks ~= 5/CU round
    if (fixed + (size_t)K * per_copy > ws_size) {
        size_t avail = (ws_size > fixed) ? (ws_size - fixed) : 0;
        int kfit = (int)(avail / per_copy);
        K = kfit < 1 ? 1 : (kfit < K ? kfit : K);
    }
    unsigned int* copies = (unsigned int*)alloc((size_t)K * per_copy);
    (void)n_in; (void)out_size;

    hipMemsetAsync(d_ws, 0, zero_bytes, stream);

    const int B = 256;
    k_hist<<<dim3(K, R), B, 0, stream>>>(esrc, edst, copies, gene_cnt, gene_src,
                                         flag, e, K, R);
    int Wtot = R * HWORDS;
    k_reduce<<<(Wtot + B - 1) / B, B, 0, stream>>>(copies, dinv, flag, n, K, Wtot);
    int e4b = (e >> 2) + 1;
    k_l1_scatter<<<(e4b + B - 1) / B, B, 0, stream>>>(esrc, edst, x, dinv, flag, t, e);
    k_gene<<<(NG + B - 1) / B, B, 0, stream>>>(gene_cnt, gene_src, t, dinv, x,
                                               W1, b1, W2, agg, NG);
    k_final<<<(NG + B - 1) / B, B, 0, stream>>>(t, dinv, x, W1, b1, W2, b2,
                                                fw1, fb1, fw2, fb2, agg,
                                                (float*)d_out, G);
}

// Round 4
// 284.416 us; speedup vs baseline: 2.2911x; 1.2824x over previous
//
#include <hip/hip_runtime.h>

#define NODES 1430
#define GENE0 1421
#define NHEADS 9
#define HBINS 65536          // bins per block; 4-bit counts, 8 per u32
#define HWORDS (HBINS / 8)   // 8192 u32 words = 32 KB LDS -> 5 blocks/CU
#define GMAX 64              // max bucketed in-edges per gene (Poisson(8) tail ~0)

__device__ __forceinline__ float frelu(float v) { return v > 0.f ? v : 0.f; }

// Pass 1: privatized LDS histogram (4-bit packed) of in-degree.
// Grid (K chunks, R ranges). r==0 blocks also bucket gene-dst edges.
__global__ void k_hist(const int* __restrict__ esrc, const int* __restrict__ edst,
                       unsigned int* __restrict__ copies,      // [K][R*HWORDS]
                       int* __restrict__ gene_cnt, int* __restrict__ gene_src,
                       unsigned char* __restrict__ flag,
                       int e, int K, int R) {
    __shared__ unsigned int lds[HWORDS];
    const int k = blockIdx.x, r = blockIdx.y;
    const int tid = threadIdx.x;
    {
        uint4* l4 = (uint4*)lds;
        for (int w = tid; w < HWORDS / 4; w += 256) l4[w] = make_uint4(0, 0, 0, 0);
    }
    __syncthreads();

    const unsigned int lo = (unsigned int)r * HBINS;
    const int e4 = e >> 2;
    const int Q = (e4 + K - 1) / K;
    const int beg = k * Q;
    const int end = min(beg + Q, e4);
    const int4* ed4 = (const int4*)edst;
    const int len = (end > beg) ? (end - beg) : 0;
    const int quarter = len >> 2;

    auto proc = [&](int j, int4 d4) {
#pragma unroll
        for (int c = 0; c < 4; c++) {
            unsigned int d = (unsigned int)((&d4.x)[c]);
            unsigned int rel = d - lo;
            if (rel < HBINS)
                atomicAdd(&lds[rel >> 3], 1u << ((rel & 7u) * 4u));
            if (r == 0) {
                unsigned int graph = d / NODES;
                unsigned int pos = d - graph * NODES;
                if (pos >= GENE0) {
                    int s = esrc[4 * j + c];
                    flag[s] = 1;
                    int g = (int)(graph * NHEADS + (pos - GENE0));
                    int p = atomicAdd(gene_cnt + g, 1);
                    if (p < GMAX) gene_src[(g << 6) + p] = s;
                }
            }
        }
    };

    // four independent streams -> 4 loads in flight per wave
    for (int i = tid; i < quarter; i += 256) {
        int j1 = beg + i;
        int j2 = j1 + quarter;
        int j3 = j2 + quarter;
        int j4 = j3 + quarter;
        int4 a = ed4[j1];
        int4 b = ed4[j2];
        int4 cc = ed4[j3];
        int4 dd = ed4[j4];
        proc(j1, a); proc(j2, b); proc(j3, cc); proc(j4, dd);
    }
    // leftover (len % 4) iterations
    for (int i = (quarter << 2) + tid; i < len; i += 256) {
        int j = beg + i;
        proc(j, ed4[j]);
    }
    // tail edges (e % 4) — chunk-0 blocks of every range
    if (k == 0) {
        for (int j = (e4 << 2) + tid; j < e; j += 256) {
            unsigned int d = (unsigned int)edst[j];
            unsigned int rel = d - lo;
            if (rel < HBINS)
                atomicAdd(&lds[rel >> 3], 1u << ((rel & 7u) * 4u));
            if (r == 0) {
                unsigned int graph = d / NODES;
                unsigned int pos = d - graph * NODES;
                if (pos >= GENE0) {
                    int s = esrc[j];
                    flag[s] = 1;
                    int g = (int)(graph * NHEADS + (pos - GENE0));
                    int p = atomicAdd(gene_cnt + g, 1);
                    if (p < GMAX) gene_src[(g << 6) + p] = s;
                }
            }
        }
    }
    __syncthreads();
    uint4* dst4 = (uint4*)(copies + ((size_t)k * R + r) * HWORDS);
    const uint4* l4 = (const uint4*)lds;
    for (int w = tid; w < HWORDS / 4; w += 256) dst4[w] = l4[w];
}

// Pass 2: sum K nibble-histograms (SWAR even/odd), dinv = rsqrt(deg+1),
// flag gene nodes. Each thread owns one word = 8 consecutive nodes.
__global__ void k_reduce(const unsigned int* __restrict__ copies,
                         float* __restrict__ dinv, unsigned char* __restrict__ flag,
                         int n, int K, int Wtot) {
    int w = blockIdx.x * blockDim.x + threadIdx.x;
    if (w >= Wtot) return;
    unsigned int evn = 0, odd = 0;
    for (int k = 0; k < K; k++) {
        unsigned int u = copies[(size_t)k * Wtot + w];
        evn += u & 0x0F0F0F0Fu;
        odd += (u >> 4) & 0x0F0F0F0Fu;
    }
    int i0 = w << 3;
    float v[8];
#pragma unroll
    for (int b = 0; b < 4; b++) {
        v[2 * b]     = (float)((evn >> (8 * b)) & 0xFFu);
        v[2 * b + 1] = (float)((odd >> (8 * b)) & 0xFFu);
    }
#pragma unroll
    for (int b = 0; b < 8; b++) v[b] = rsqrtf(v[b] + 1.f);
    if (i0 + 7 < n) {
        float4 lo4 = {v[0], v[1], v[2], v[3]};
        float4 hi4 = {v[4], v[5], v[6], v[7]};
        *(float4*)(dinv + i0) = lo4;
        *(float4*)(dinv + i0 + 4) = hi4;
    } else {
        for (int b = 0; b < 8; b++) if (i0 + b < n) dinv[i0 + b] = v[b];
    }
#pragma unroll
    for (int b = 0; b < 8; b++) {
        int i = i0 + b;
        if (i < n) {
            unsigned int graph = (unsigned int)i / NODES;
            unsigned int pos = (unsigned int)i - graph * NODES;
            if (pos >= GENE0) flag[i] = 1;
        }
    }
}

// Pass 3: scalar layer-1 scatter into flagged dst only (~5.6% of edges).
// Both edge arrays read as streaming int4 so the only flag-dependent loads
// are the dinv/x gathers on actual hits.
__global__ void k_l1_scatter(const int* __restrict__ esrc, const int* __restrict__ edst,
                             const float* __restrict__ x, const float* __restrict__ dinv,
                             const unsigned char* __restrict__ flag,
                             float* __restrict__ t, int e) {
    int q = blockIdx.x * blockDim.x + threadIdx.x;
    int e4 = e >> 2;
    if (q < e4) {
        int4 d4 = ((const int4*)edst)[q];
        int4 s4 = ((const int4*)esrc)[q];
#pragma unroll
        for (int c = 0; c < 4; c++) {
            int d = (&d4.x)[c];
            if (!flag[d]) continue;
            int s = (&s4.x)[c];
            atomicAdd(t + d, dinv[s] * dinv[d] * x[s]);
        }
    } else if (q == e4) {
        for (int j = e4 << 2; j < e; j++) {
            int d = edst[j];
            if (!flag[d]) continue;
            int s = esrc[j];
            atomicAdd(t + d, dinv[s] * dinv[d] * x[s]);
        }
    }
}

// Pass 4 (fused 4+5): one WAVE per gene. Lane i handles bucketed edge i
// (parallel gathers), butterfly-reduce the 16-float contribution, lane 0
// finalizes (self-loop + bias + relu) and runs the per-head 16->8->1 MLP.
__global__ void k_gene_final(const int* __restrict__ gene_cnt, const int* __restrict__ gene_src,
                             const float* __restrict__ t, const float* __restrict__ dinv,
                             const float* __restrict__ x,
                             const float* __restrict__ W1, const float* __restrict__ b1,
                             const float* __restrict__ W2, const float* __restrict__ b2,
                             const float* __restrict__ fw1, const float* __restrict__ fb1,
                             const float* __restrict__ fw2, const float* __restrict__ fb2,
                             float* __restrict__ out, int NG, int G) {
    int wid = (blockIdx.x * blockDim.x + threadIdx.x) >> 6;
    int lane = threadIdx.x & 63;
    if (wid >= NG) return;
    int g = wid;
    int graph = g / NHEADS;
    int head = g - graph * NHEADS;
    int node = graph * NODES + GENE0 + head;
    int cnt = min(gene_cnt[g], GMAX);

    float contrib[16];
#pragma unroll
    for (int c = 0; c < 16; c++) contrib[c] = 0.f;
    if (lane < cnt) {
        int s = gene_src[(g << 6) + lane];
        float ds = dinv[s];
        float us = t[s] + ds * ds * x[s];
        float l1[16];
#pragma unroll
        for (int kk = 0; kk < 16; kk++) l1[kk] = frelu(us * W1[kk] + b1[kk]);
#pragma unroll
        for (int c = 0; c < 16; c++) {
            float m = 0.f;
#pragma unroll
            for (int kk = 0; kk < 16; kk++) m += l1[kk] * W2[kk * 16 + c];
            contrib[c] = ds * m;
        }
    }
    // butterfly reduce across the wave
#pragma unroll
    for (int off = 32; off > 0; off >>= 1) {
#pragma unroll
        for (int c = 0; c < 16; c++)
            contrib[c] += __shfl_xor(contrib[c], off, 64);
    }
    if (lane == 0) {
        float dn = dinv[node];
        float un = t[node] + dn * dn * x[node];
        float l1[16];
#pragma unroll
        for (int kk = 0; kk < 16; kk++) l1[kk] = frelu(un * W1[kk] + b1[kk]);
        float dsq = dn * dn;
        float h[16];
#pragma unroll
        for (int c = 0; c < 16; c++) {
            float h2 = 0.f;
#pragma unroll
            for (int kk = 0; kk < 16; kk++) h2 += l1[kk] * W2[kk * 16 + c];
            h[c] = frelu(dn * contrib[c] + dsq * h2 + b2[c]);
        }
        float pred = fb2[head];
#pragma unroll
        for (int kk = 0; kk < 8; kk++) {
            float z = fb1[head * 8 + kk];
#pragma unroll
            for (int c = 0; c < 16; c++) z += h[c] * fw1[head * 128 + c * 8 + kk];
            pred += frelu(z) * fw2[head * 8 + kk];
        }
        out[head * G + graph] = pred;
    }
}

extern "C" void kernel_launch(void* const* d_in, const int* in_sizes, int n_in,
                              void* d_out, int out_size, void* d_ws, size_t ws_size,
                              hipStream_t stream) {
    const float* x   = (const float*)d_in[0];
    const int*   ei  = (const int*)d_in[1];
    const float* W1  = (const float*)d_in[3];
    const float* b1  = (const float*)d_in[4];
    const float* W2  = (const float*)d_in[5];
    const float* b2  = (const float*)d_in[6];
    const float* fw1 = (const float*)d_in[7];
    const float* fb1 = (const float*)d_in[8];
    const float* fw2 = (const float*)d_in[9];
    const float* fb2 = (const float*)d_in[10];

    int n = in_sizes[0];
    int e = in_sizes[1] / 2;
    int G = in_sizes[2] / NHEADS;
    int NG = G * NHEADS;
    const int* esrc = ei;
    const int* edst = ei + e;

    char* ws = (char*)d_ws;
    size_t off = 0;
    auto alloc = [&](size_t bytes) {
        char* p = ws + off;
        off += (bytes + 255) & ~(size_t)255;
        return p;
    };
    // zero-init region first
    float* t             = (float*)alloc((size_t)n * 4);
    int*   gene_cnt      = (int*)alloc((size_t)NG * 4);
    unsigned char* flag  = (unsigned char*)alloc((size_t)n);
    size_t zero_bytes    = off;
    // written-before-read region
    float* dinv          = (float*)alloc((size_t)n * 4);
    int*   gene_src      = (int*)alloc((size_t)NG * GMAX * 4);
    size_t fixed         = off;

    int R = (n + HBINS - 1) / HBINS;                  // 12 for n=732160
    size_t per_copy = (size_t)R * HWORDS * 4;         // 384 KB per chunk
    int K = 106;                                      // K*R = 1272 blocks ~= 5/CU round
    if (fixed + (size_t)K * per_copy > ws_size) {
        size_t avail = (ws_size > fixed) ? (ws_size - fixed) : 0;
        int kfit = (int)(avail / per_copy);
        K = kfit < 1 ? 1 : (kfit < K ? kfit : K);
    }
    unsigned int* copies = (unsigned int*)alloc((size_t)K * per_copy);
    (void)n_in; (void)out_size;

    hipMemsetAsync(d_ws, 0, zero_bytes, stream);

    const int B = 256;
    k_hist<<<dim3(K, R), B, 0, stream>>>(esrc, edst, copies, gene_cnt, gene_src,
                                         flag, e, K, R);
    int Wtot = R * HWORDS;
    k_reduce<<<(Wtot + B - 1) / B, B, 0, stream>>>(copies, dinv, flag, n, K, Wtot);
    int e4b = (e >> 2) + 1;
    k_l1_scatter<<<(e4b + B - 1) / B, B, 0, stream>>>(esrc, edst, x, dinv, flag, t, e);
    int waves_blocks = (NG * 64 + B - 1) / B;
    k_gene_final<<<waves_blocks, B, 0, stream>>>(gene_cnt, gene_src, t, dinv, x,
                                                 W1, b1, W2, b2,
                                                 fw1, fb1, fw2, fb2,
                                                 (float*)d_out, NG, G);
}

// Round 5
// 244.489 us; speedup vs baseline: 2.6653x; 1.1633x over previous
//
#include <hip/hip_runtime.h>

#define NODES 1430
#define GENE0 1421
#define NHEADS 9
#define HBINS 131072         // bins per block; 4-bit counts, 8 per u32
#define HWORDS (HBINS / 8)   // 16384 u32 words = 64 KB LDS
#define BHIST 1024           // 16 waves/block; 2 blocks/CU -> 32 waves/CU
#define GMAX 64              // max bucketed in-edges per gene (Poisson(8) tail ~0)

__device__ __forceinline__ float frelu(float v) { return v > 0.f ? v : 0.f; }

// Pass 1: privatized LDS histogram (4-bit packed) of in-degree.
// Grid (K chunks, R ranges), 1024-thread blocks. r==0 blocks also bucket
// gene-dst edges and flag their srcs.
__global__ __launch_bounds__(BHIST, 4)
void k_hist(const int* __restrict__ esrc, const int* __restrict__ edst,
            unsigned int* __restrict__ copies,      // [K][R*HWORDS]
            int* __restrict__ gene_cnt, int* __restrict__ gene_src,
            unsigned char* __restrict__ flag,
            int e, int K, int R) {
    __shared__ unsigned int lds[HWORDS];
    const int k = blockIdx.x, r = blockIdx.y;
    const int tid = threadIdx.x;
    {
        uint4* l4 = (uint4*)lds;
        for (int w = tid; w < HWORDS / 4; w += BHIST) l4[w] = make_uint4(0, 0, 0, 0);
    }
    __syncthreads();

    const unsigned int lo = (unsigned int)r * HBINS;
    const int e4 = e >> 2;
    const int Q = (e4 + K - 1) / K;
    const int beg = k * Q;
    const int end = min(beg + Q, e4);
    const int4* ed4 = (const int4*)edst;
    const int len = (end > beg) ? (end - beg) : 0;
    const int quarter = len >> 2;

    auto proc = [&](int j, int4 d4) {
#pragma unroll
        for (int c = 0; c < 4; c++) {
            unsigned int d = (unsigned int)((&d4.x)[c]);
            unsigned int rel = d - lo;
            if (rel < HBINS)
                atomicAdd(&lds[rel >> 3], 1u << ((rel & 7u) * 4u));
            if (r == 0) {
                unsigned int graph = d / NODES;
                unsigned int pos = d - graph * NODES;
                if (pos >= GENE0) {
                    int s = esrc[4 * j + c];
                    flag[s] = 1;
                    int g = (int)(graph * NHEADS + (pos - GENE0));
                    int p = atomicAdd(gene_cnt + g, 1);
                    if (p < GMAX) gene_src[(g << 6) + p] = s;
                }
            }
        }
    };

    // four independent streams -> 4 int4 loads in flight per wave
    for (int i = tid; i < quarter; i += BHIST) {
        int j1 = beg + i;
        int j2 = j1 + quarter;
        int j3 = j2 + quarter;
        int j4 = j3 + quarter;
        int4 a = ed4[j1];
        int4 b = ed4[j2];
        int4 cc = ed4[j3];
        int4 dd = ed4[j4];
        proc(j1, a); proc(j2, b); proc(j3, cc); proc(j4, dd);
    }
    for (int i = (quarter << 2) + tid; i < len; i += BHIST) {
        int j = beg + i;
        proc(j, ed4[j]);
    }
    // tail edges (e % 4) — chunk-0 blocks of every range
    if (k == 0) {
        for (int j = (e4 << 2) + tid; j < e; j += BHIST) {
            unsigned int d = (unsigned int)edst[j];
            unsigned int rel = d - lo;
            if (rel < HBINS)
                atomicAdd(&lds[rel >> 3], 1u << ((rel & 7u) * 4u));
            if (r == 0) {
                unsigned int graph = d / NODES;
                unsigned int pos = d - graph * NODES;
                if (pos >= GENE0) {
                    int s = esrc[j];
                    flag[s] = 1;
                    int g = (int)(graph * NHEADS + (pos - GENE0));
                    int p = atomicAdd(gene_cnt + g, 1);
                    if (p < GMAX) gene_src[(g << 6) + p] = s;
                }
            }
        }
    }
    __syncthreads();
    uint4* dst4 = (uint4*)(copies + ((size_t)k * R + r) * HWORDS);
    const uint4* l4 = (const uint4*)lds;
    for (int w = tid; w < HWORDS / 4; w += BHIST) dst4[w] = l4[w];
}

// Pass 2: sum K nibble-histograms (SWAR even/odd), dinv = rsqrt(deg+1),
// flag gene nodes. Each thread owns one word = 8 consecutive nodes.
__global__ void k_reduce(const unsigned int* __restrict__ copies,
                         float* __restrict__ dinv, unsigned char* __restrict__ flag,
                         int n, int K, int Wtot) {
    int w = blockIdx.x * blockDim.x + threadIdx.x;
    if (w >= Wtot) return;
    unsigned int evn = 0, odd = 0;
    for (int k = 0; k < K; k++) {
        unsigned int u = copies[(size_t)k * Wtot + w];
        evn += u & 0x0F0F0F0Fu;
        odd += (u >> 4) & 0x0F0F0F0Fu;
    }
    int i0 = w << 3;
    float v[8];
#pragma unroll
    for (int b = 0; b < 4; b++) {
        v[2 * b]     = (float)((evn >> (8 * b)) & 0xFFu);
        v[2 * b + 1] = (float)((odd >> (8 * b)) & 0xFFu);
    }
#pragma unroll
    for (int b = 0; b < 8; b++) v[b] = rsqrtf(v[b] + 1.f);
    if (i0 + 7 < n) {
        float4 lo4 = {v[0], v[1], v[2], v[3]};
        float4 hi4 = {v[4], v[5], v[6], v[7]};
        *(float4*)(dinv + i0) = lo4;
        *(float4*)(dinv + i0 + 4) = hi4;
    } else {
        for (int b = 0; b < 8; b++) if (i0 + b < n) dinv[i0 + b] = v[b];
    }
#pragma unroll
    for (int b = 0; b < 8; b++) {
        int i = i0 + b;
        if (i < n) {
            unsigned int graph = (unsigned int)i / NODES;
            unsigned int pos = (unsigned int)i - graph * NODES;
            if (pos >= GENE0) flag[i] = 1;
        }
    }
}

// Pass 3: scalar layer-1 scatter into flagged dst only (~5.6% of edges),
// 8 edges/thread (two independent int4 pairs in flight).
__global__ void k_l1_scatter(const int* __restrict__ esrc, const int* __restrict__ edst,
                             const float* __restrict__ x, const float* __restrict__ dinv,
                             const unsigned char* __restrict__ flag,
                             float* __restrict__ t, int e) {
    int q = blockIdx.x * blockDim.x + threadIdx.x;
    int e8 = e >> 3;
    if (q < e8) {
        const int4* ed4 = (const int4*)edst;
        const int4* es4 = (const int4*)esrc;
        int4 da = ed4[2 * q];
        int4 db = ed4[2 * q + 1];
        int4 sa = es4[2 * q];
        int4 sb = es4[2 * q + 1];
#pragma unroll
        for (int c = 0; c < 4; c++) {
            int d = (&da.x)[c];
            if (flag[d]) {
                int s = (&sa.x)[c];
                atomicAdd(t + d, dinv[s] * dinv[d] * x[s]);
            }
        }
#pragma unroll
        for (int c = 0; c < 4; c++) {
            int d = (&db.x)[c];
            if (flag[d]) {
                int s = (&sb.x)[c];
                atomicAdd(t + d, dinv[s] * dinv[d] * x[s]);
            }
        }
    } else if (q == e8) {
        for (int j = e8 << 3; j < e; j++) {
            int d = edst[j];
            if (!flag[d]) continue;
            int s = esrc[j];
            atomicAdd(t + d, dinv[s] * dinv[d] * x[s]);
        }
    }
}

// Pass 4 (fused): one WAVE per gene. Lane i handles bucketed edge i,
// butterfly-reduce, lane 0 finalizes + per-head 16->8->1 MLP.
__global__ void k_gene_final(const int* __restrict__ gene_cnt, const int* __restrict__ gene_src,
                             const float* __restrict__ t, const float* __restrict__ dinv,
                             const float* __restrict__ x,
                             const float* __restrict__ W1, const float* __restrict__ b1,
                             const float* __restrict__ W2, const float* __restrict__ b2,
                             const float* __restrict__ fw1, const float* __restrict__ fb1,
                             const float* __restrict__ fw2, const float* __restrict__ fb2,
                             float* __restrict__ out, int NG, int G) {
    int wid = (blockIdx.x * blockDim.x + threadIdx.x) >> 6;
    int lane = threadIdx.x & 63;
    if (wid >= NG) return;
    int g = wid;
    int graph = g / NHEADS;
    int head = g - graph * NHEADS;
    int node = graph * NODES + GENE0 + head;
    int cnt = min(gene_cnt[g], GMAX);

    float contrib[16];
#pragma unroll
    for (int c = 0; c < 16; c++) contrib[c] = 0.f;
    if (lane < cnt) {
        int s = gene_src[(g << 6) + lane];
        float ds = dinv[s];
        float us = t[s] + ds * ds * x[s];
        float l1[16];
#pragma unroll
        for (int kk = 0; kk < 16; kk++) l1[kk] = frelu(us * W1[kk] + b1[kk]);
#pragma unroll
        for (int c = 0; c < 16; c++) {
            float m = 0.f;
#pragma unroll
            for (int kk = 0; kk < 16; kk++) m += l1[kk] * W2[kk * 16 + c];
            contrib[c] = ds * m;
        }
    }
#pragma unroll
    for (int off = 32; off > 0; off >>= 1) {
#pragma unroll
        for (int c = 0; c < 16; c++)
            contrib[c] += __shfl_xor(contrib[c], off, 64);
    }
    if (lane == 0) {
        float dn = dinv[node];
        float un = t[node] + dn * dn * x[node];
        float l1[16];
#pragma unroll
        for (int kk = 0; kk < 16; kk++) l1[kk] = frelu(un * W1[kk] + b1[kk]);
        float dsq = dn * dn;
        float h[16];
#pragma unroll
        for (int c = 0; c < 16; c++) {
            float h2 = 0.f;
#pragma unroll
            for (int kk = 0; kk < 16; kk++) h2 += l1[kk] * W2[kk * 16 + c];
            h[c] = frelu(dn * contrib[c] + dsq * h2 + b2[c]);
        }
        float pred = fb2[head];
#pragma unroll
        for (int kk = 0; kk < 8; kk++) {
            float z = fb1[head * 8 + kk];
#pragma unroll
            for (int c = 0; c < 16; c++) z += h[c] * fw1[head * 128 + c * 8 + kk];
            pred += frelu(z) * fw2[head * 8 + kk];
        }
        out[head * G + graph] = pred;
    }
}

extern "C" void kernel_launch(void* const* d_in, const int* in_sizes, int n_in,
                              void* d_out, int out_size, void* d_ws, size_t ws_size,
                              hipStream_t stream) {
    const float* x   = (const float*)d_in[0];
    const int*   ei  = (const int*)d_in[1];
    const float* W1  = (const float*)d_in[3];
    const float* b1  = (const float*)d_in[4];
    const float* W2  = (const float*)d_in[5];
    const float* b2  = (const float*)d_in[6];
    const float* fw1 = (const float*)d_in[7];
    const float* fb1 = (const float*)d_in[8];
    const float* fw2 = (const float*)d_in[9];
    const float* fb2 = (const float*)d_in[10];

    int n = in_sizes[0];
    int e = in_sizes[1] / 2;
    int G = in_sizes[2] / NHEADS;
    int NG = G * NHEADS;
    const int* esrc = ei;
    const int* edst = ei + e;

    char* ws = (char*)d_ws;
    size_t off = 0;
    auto alloc = [&](size_t bytes) {
        char* p = ws + off;
        off += (bytes + 255) & ~(size_t)255;
        return p;
    };
    // zero-init region first
    float* t             = (float*)alloc((size_t)n * 4);
    int*   gene_cnt      = (int*)alloc((size_t)NG * 4);
    unsigned char* flag  = (unsigned char*)alloc((size_t)n);
    size_t zero_bytes    = off;
    // written-before-read region
    float* dinv          = (float*)alloc((size_t)n * 4);
    int*   gene_src      = (int*)alloc((size_t)NG * GMAX * 4);
    size_t fixed         = off;

    int R = (n + HBINS - 1) / HBINS;                  // 6 for n=732160
    size_t per_copy = (size_t)R * HWORDS * 4;         // 384 KB per chunk
    int K = 85;                                       // K*R = 510 ~= one 2-blocks/CU round
    if (fixed + (size_t)K * per_copy > ws_size) {
        size_t avail = (ws_size > fixed) ? (ws_size - fixed) : 0;
        int kfit = (int)(avail / per_copy);
        K = kfit < 1 ? 1 : (kfit < K ? kfit : K);
    }
    unsigned int* copies = (unsigned int*)alloc((size_t)K * per_copy);
    (void)n_in; (void)out_size;

    hipMemsetAsync(d_ws, 0, zero_bytes, stream);

    const int B = 256;
    k_hist<<<dim3(K, R), BHIST, 0, stream>>>(esrc, edst, copies, gene_cnt, gene_src,
                                             flag, e, K, R);
    int Wtot = R * HWORDS;
    k_reduce<<<(Wtot + B - 1) / B, B, 0, stream>>>(copies, dinv, flag, n, K, Wtot);
    int e8b = (e >> 3) + 1;
    k_l1_scatter<<<(e8b + B - 1) / B, B, 0, stream>>>(esrc, edst, x, dinv, flag, t, e);
    int waves_blocks = (NG * 64 + B - 1) / B;
    k_gene_final<<<waves_blocks, B, 0, stream>>>(gene_cnt, gene_src, t, dinv, x,
                                                 W1, b1, W2, b2,
                                                 fw1, fb1, fw2, fb2,
                                                 (float*)d_out, NG, G);
}

// Round 6
// 230.961 us; speedup vs baseline: 2.8214x; 1.0586x over previous
//
#include <hip/hip_runtime.h>

#define NODES 1430
#define GENE0 1421
#define NHEADS 9
#define HBINS 131072         // bins per block; 4-bit counts, 8 per u32
#define HWORDS (HBINS / 8)   // 16384 u32 words = 64 KB LDS
#define BHIST 1024           // 16 waves/block; 2 blocks/CU -> 32 waves/CU
#define GMAX 64              // max bucketed in-edges per gene (Poisson(8) tail ~0)

__device__ __forceinline__ float frelu(float v) { return v > 0.f ? v : 0.f; }

// Pass 1: privatized LDS histogram (4-bit packed) of in-degree.
// Grid (K chunks, R ranges), 1024-thread blocks, 8 independent load streams.
// r==0 blocks also bucket gene-dst edges and set src bits in the flag bitmask.
__global__ __launch_bounds__(BHIST, 8)
void k_hist(const int* __restrict__ esrc, const int* __restrict__ edst,
            unsigned int* __restrict__ copies,      // [K][R*HWORDS]
            int* __restrict__ gene_cnt, int* __restrict__ gene_src,
            unsigned int* __restrict__ flagw,
            int e, int K, int R) {
    __shared__ unsigned int lds[HWORDS];
    const int k = blockIdx.x, r = blockIdx.y;
    const int tid = threadIdx.x;
    {
        uint4* l4 = (uint4*)lds;
        for (int w = tid; w < HWORDS / 4; w += BHIST) l4[w] = make_uint4(0, 0, 0, 0);
    }
    __syncthreads();

    const unsigned int lo = (unsigned int)r * HBINS;
    const int e4 = e >> 2;
    const int Q = (e4 + K - 1) / K;
    const int beg = k * Q;
    const int end = min(beg + Q, e4);
    const int4* ed4 = (const int4*)edst;
    const int len = (end > beg) ? (end - beg) : 0;
    const int eighth = len >> 3;

    auto proc = [&](int j, int4 d4) {
#pragma unroll
        for (int c = 0; c < 4; c++) {
            unsigned int d = (unsigned int)((&d4.x)[c]);
            unsigned int rel = d - lo;
            if (rel < HBINS)
                atomicAdd(&lds[rel >> 3], 1u << ((rel & 7u) * 4u));
            if (r == 0) {
                unsigned int graph = d / NODES;
                unsigned int pos = d - graph * NODES;
                if (pos >= GENE0) {
                    int s = esrc[4 * j + c];
                    atomicOr(&flagw[(unsigned)s >> 5], 1u << (s & 31));
                    int g = (int)(graph * NHEADS + (pos - GENE0));
                    int p = atomicAdd(gene_cnt + g, 1);
                    if (p < GMAX) gene_src[(g << 6) + p] = s;
                }
            }
        }
    };

    // eight independent streams -> 8 int4 loads in flight per wave
    for (int i = tid; i < eighth; i += BHIST) {
        int j0 = beg + i;
        int4 v0 = ed4[j0];
        int4 v1 = ed4[j0 + eighth];
        int4 v2 = ed4[j0 + 2 * eighth];
        int4 v3 = ed4[j0 + 3 * eighth];
        int4 v4 = ed4[j0 + 4 * eighth];
        int4 v5 = ed4[j0 + 5 * eighth];
        int4 v6 = ed4[j0 + 6 * eighth];
        int4 v7 = ed4[j0 + 7 * eighth];
        proc(j0, v0);
        proc(j0 + eighth, v1);
        proc(j0 + 2 * eighth, v2);
        proc(j0 + 3 * eighth, v3);
        proc(j0 + 4 * eighth, v4);
        proc(j0 + 5 * eighth, v5);
        proc(j0 + 6 * eighth, v6);
        proc(j0 + 7 * eighth, v7);
    }
    for (int i = (eighth << 3) + tid; i < len; i += BHIST) {
        int j = beg + i;
        proc(j, ed4[j]);
    }
    // tail edges (e % 4) — chunk-0 blocks of every range
    if (k == 0) {
        for (int j = (e4 << 2) + tid; j < e; j += BHIST) {
            unsigned int d = (unsigned int)edst[j];
            unsigned int rel = d - lo;
            if (rel < HBINS)
                atomicAdd(&lds[rel >> 3], 1u << ((rel & 7u) * 4u));
            if (r == 0) {
                unsigned int graph = d / NODES;
                unsigned int pos = d - graph * NODES;
                if (pos >= GENE0) {
                    int s = esrc[j];
                    atomicOr(&flagw[(unsigned)s >> 5], 1u << (s & 31));
                    int g = (int)(graph * NHEADS + (pos - GENE0));
                    int p = atomicAdd(gene_cnt + g, 1);
                    if (p < GMAX) gene_src[(g << 6) + p] = s;
                }
            }
        }
    }
    __syncthreads();
    uint4* dst4 = (uint4*)(copies + ((size_t)k * R + r) * HWORDS);
    const uint4* l4 = (const uint4*)lds;
    for (int w = tid; w < HWORDS / 4; w += BHIST) dst4[w] = l4[w];
}

// Pass 2: sum K nibble-histograms (SWAR, 4-way k-unroll for MLP),
// dinv = rsqrt(deg+1), set gene-node bits in the flag mask.
__global__ void k_reduce(const unsigned int* __restrict__ copies,
                         float* __restrict__ dinv, unsigned int* __restrict__ flagw,
                         int n, int K, int Wtot) {
    int w = blockIdx.x * blockDim.x + threadIdx.x;
    if (w >= Wtot) return;
    const unsigned int M = 0x0F0F0F0Fu;
    unsigned int e0 = 0, o0 = 0, e1 = 0, o1 = 0, e2 = 0, o2 = 0, e3 = 0, o3 = 0;
    int k = 0;
    for (; k + 4 <= K; k += 4) {
        unsigned int u0 = copies[(size_t)(k + 0) * Wtot + w];
        unsigned int u1 = copies[(size_t)(k + 1) * Wtot + w];
        unsigned int u2 = copies[(size_t)(k + 2) * Wtot + w];
        unsigned int u3 = copies[(size_t)(k + 3) * Wtot + w];
        e0 += u0 & M; o0 += (u0 >> 4) & M;
        e1 += u1 & M; o1 += (u1 >> 4) & M;
        e2 += u2 & M; o2 += (u2 >> 4) & M;
        e3 += u3 & M; o3 += (u3 >> 4) & M;
    }
    for (; k < K; k++) {
        unsigned int u = copies[(size_t)k * Wtot + w];
        e0 += u & M; o0 += (u >> 4) & M;
    }
    unsigned int evn = e0 + e1 + e2 + e3;   // byte lanes: sum == node degree <= ~40
    unsigned int odd = o0 + o1 + o2 + o3;
    int i0 = w << 3;
    float v[8];
#pragma unroll
    for (int b = 0; b < 4; b++) {
        v[2 * b]     = (float)((evn >> (8 * b)) & 0xFFu);
        v[2 * b + 1] = (float)((odd >> (8 * b)) & 0xFFu);
    }
#pragma unroll
    for (int b = 0; b < 8; b++) v[b] = rsqrtf(v[b] + 1.f);
    if (i0 + 7 < n) {
        float4 lo4 = {v[0], v[1], v[2], v[3]};
        float4 hi4 = {v[4], v[5], v[6], v[7]};
        *(float4*)(dinv + i0) = lo4;
        *(float4*)(dinv + i0 + 4) = hi4;
    } else {
        for (int b = 0; b < 8; b++) if (i0 + b < n) dinv[i0 + b] = v[b];
    }
#pragma unroll
    for (int b = 0; b < 8; b++) {
        int i = i0 + b;
        if (i < n) {
            unsigned int graph = (unsigned int)i / NODES;
            unsigned int pos = (unsigned int)i - graph * NODES;
            if (pos >= GENE0) atomicOr(&flagw[(unsigned)i >> 5], 1u << (i & 31));
        }
    }
}

// Pass 3: scalar layer-1 scatter into flagged dst only (~5.6% of edges).
// Flag probe is a bit test in a 91.5 KB mask (L1/L2-resident).
__global__ void k_l1_scatter(const int* __restrict__ esrc, const int* __restrict__ edst,
                             const float* __restrict__ x, const float* __restrict__ dinv,
                             const unsigned int* __restrict__ flagw,
                             float* __restrict__ t, int e) {
    int q = blockIdx.x * blockDim.x + threadIdx.x;
    int e8 = e >> 3;
    if (q < e8) {
        const int4* ed4 = (const int4*)edst;
        const int4* es4 = (const int4*)esrc;
        int4 da = ed4[2 * q];
        int4 db = ed4[2 * q + 1];
        int4 sa = es4[2 * q];
        int4 sb = es4[2 * q + 1];
#pragma unroll
        for (int c = 0; c < 4; c++) {
            int d = (&da.x)[c];
            if ((flagw[(unsigned)d >> 5] >> (d & 31)) & 1u) {
                int s = (&sa.x)[c];
                atomicAdd(t + d, dinv[s] * dinv[d] * x[s]);
            }
        }
#pragma unroll
        for (int c = 0; c < 4; c++) {
            int d = (&db.x)[c];
            if ((flagw[(unsigned)d >> 5] >> (d & 31)) & 1u) {
                int s = (&sb.x)[c];
                atomicAdd(t + d, dinv[s] * dinv[d] * x[s]);
            }
        }
    } else if (q == e8) {
        for (int j = e8 << 3; j < e; j++) {
            int d = edst[j];
            if (!((flagw[(unsigned)d >> 5] >> (d & 31)) & 1u)) continue;
            int s = esrc[j];
            atomicAdd(t + d, dinv[s] * dinv[d] * x[s]);
        }
    }
}

// Pass 4 (fused): one WAVE per gene. Lane i handles bucketed edge i,
// butterfly-reduce, lane 0 finalizes + per-head 16->8->1 MLP.
__global__ void k_gene_final(const int* __restrict__ gene_cnt, const int* __restrict__ gene_src,
                             const float* __restrict__ t, const float* __restrict__ dinv,
                             const float* __restrict__ x,
                             const float* __restrict__ W1, const float* __restrict__ b1,
                             const float* __restrict__ W2, const float* __restrict__ b2,
                             const float* __restrict__ fw1, const float* __restrict__ fb1,
                             const float* __restrict__ fw2, const float* __restrict__ fb2,
                             float* __restrict__ out, int NG, int G) {
    int wid = (blockIdx.x * blockDim.x + threadIdx.x) >> 6;
    int lane = threadIdx.x & 63;
    if (wid >= NG) return;
    int g = wid;
    int graph = g / NHEADS;
    int head = g - graph * NHEADS;
    int node = graph * NODES + GENE0 + head;
    int cnt = min(gene_cnt[g], GMAX);

    float contrib[16];
#pragma unroll
    for (int c = 0; c < 16; c++) contrib[c] = 0.f;
    if (lane < cnt) {
        int s = gene_src[(g << 6) + lane];
        float ds = dinv[s];
        float us = t[s] + ds * ds * x[s];
        float l1[16];
#pragma unroll
        for (int kk = 0; kk < 16; kk++) l1[kk] = frelu(us * W1[kk] + b1[kk]);
#pragma unroll
        for (int c = 0; c < 16; c++) {
            float m = 0.f;
#pragma unroll
            for (int kk = 0; kk < 16; kk++) m += l1[kk] * W2[kk * 16 + c];
            contrib[c] = ds * m;
        }
    }
#pragma unroll
    for (int off = 32; off > 0; off >>= 1) {
#pragma unroll
        for (int c = 0; c < 16; c++)
            contrib[c] += __shfl_xor(contrib[c], off, 64);
    }
    if (lane == 0) {
        float dn = dinv[node];
        float un = t[node] + dn * dn * x[node];
        float l1[16];
#pragma unroll
        for (int kk = 0; kk < 16; kk++) l1[kk] = frelu(un * W1[kk] + b1[kk]);
        float dsq = dn * dn;
        float h[16];
#pragma unroll
        for (int c = 0; c < 16; c++) {
            float h2 = 0.f;
#pragma unroll
            for (int kk = 0; kk < 16; kk++) h2 += l1[kk] * W2[kk * 16 + c];
            h[c] = frelu(dn * contrib[c] + dsq * h2 + b2[c]);
        }
        float pred = fb2[head];
#pragma unroll
        for (int kk = 0; kk < 8; kk++) {
            float z = fb1[head * 8 + kk];
#pragma unroll
            for (int c = 0; c < 16; c++) z += h[c] * fw1[head * 128 + c * 8 + kk];
            pred += frelu(z) * fw2[head * 8 + kk];
        }
        out[head * G + graph] = pred;
    }
}

extern "C" void kernel_launch(void* const* d_in, const int* in_sizes, int n_in,
                              void* d_out, int out_size, void* d_ws, size_t ws_size,
                              hipStream_t stream) {
    const float* x   = (const float*)d_in[0];
    const int*   ei  = (const int*)d_in[1];
    const float* W1  = (const float*)d_in[3];
    const float* b1  = (const float*)d_in[4];
    const float* W2  = (const float*)d_in[5];
    const float* b2  = (const float*)d_in[6];
    const float* fw1 = (const float*)d_in[7];
    const float* fb1 = (const float*)d_in[8];
    const float* fw2 = (const float*)d_in[9];
    const float* fb2 = (const float*)d_in[10];

    int n = in_sizes[0];
    int e = in_sizes[1] / 2;
    int G = in_sizes[2] / NHEADS;
    int NG = G * NHEADS;
    const int* esrc = ei;
    const int* edst = ei + e;

    char* ws = (char*)d_ws;
    size_t off = 0;
    auto alloc = [&](size_t bytes) {
        char* p = ws + off;
        off += (bytes + 255) & ~(size_t)255;
        return p;
    };
    // zero-init region first
    float* t             = (float*)alloc((size_t)n * 4);
    int*   gene_cnt      = (int*)alloc((size_t)NG * 4);
    unsigned int* flagw  = (unsigned int*)alloc((size_t)((n + 31) / 32) * 4);
    size_t zero_bytes    = off;
    // written-before-read region
    float* dinv          = (float*)alloc((size_t)n * 4);
    int*   gene_src      = (int*)alloc((size_t)NG * GMAX * 4);
    size_t fixed         = off;

    int R = (n + HBINS - 1) / HBINS;                  // 6 for n=732160
    size_t per_copy = (size_t)R * HWORDS * 4;         // 384 KB per chunk
    int K = 85;                                       // K*R = 510 ~= one 2-blocks/CU round
    if (fixed + (size_t)K * per_copy > ws_size) {
        size_t avail = (ws_size > fixed) ? (ws_size - fixed) : 0;
        int kfit = (int)(avail / per_copy);
        K = kfit < 1 ? 1 : (kfit < K ? kfit : K);
    }
    unsigned int* copies = (unsigned int*)alloc((size_t)K * per_copy);
    (void)n_in; (void)out_size;

    hipMemsetAsync(d_ws, 0, zero_bytes, stream);

    const int B = 256;
    k_hist<<<dim3(K, R), BHIST, 0, stream>>>(esrc, edst, copies, gene_cnt, gene_src,
                                             flagw, e, K, R);
    int Wtot = R * HWORDS;
    k_reduce<<<(Wtot + B - 1) / B, B, 0, stream>>>(copies, dinv, flagw, n, K, Wtot);
    int e8b = (e >> 3) + 1;
    k_l1_scatter<<<(e8b + B - 1) / B, B, 0, stream>>>(esrc, edst, x, dinv, flagw, t, e);
    int waves_blocks = (NG * 64 + B - 1) / B;
    k_gene_final<<<waves_blocks, B, 0, stream>>>(gene_cnt, gene_src, t, dinv, x,
                                                 W1, b1, W2, b2,
                                                 fw1, fb1, fw2, fb2,
                                                 (float*)d_out, NG, G);
}

// Round 7
// 225.970 us; speedup vs baseline: 2.8837x; 1.0221x over previous
//
#include <hip/hip_runtime.h>

#define NODES 1430
#define GENE0 1421
#define NHEADS 9
#define HBINS 131072         // bins per block; 4-bit counts, 8 per u32
#define HWORDS (HBINS / 8)   // 16384 u32 words = 64 KB LDS (gfx9 per-WG max)
#define BHIST 1024           // 16 waves/block; 2 blocks/CU thread-cap
#define GMAX 64              // max bucketed in-edges per gene (Poisson(8) tail ~0)

__device__ __forceinline__ float frelu(float v) { return v > 0.f ? v : 0.f; }

// Pass 1: privatized LDS histogram (4-bit packed) of in-degree.
// Grid (R ranges, K chunks) — x = range so the 6 blocks sharing one edge
// chunk are dispatched consecutively (same XCD -> L2 reuse of the chunk).
// r==0 blocks also bucket gene-dst edges and set src bits in the flag mask.
__global__ __launch_bounds__(BHIST, 4)
void k_hist(const int* __restrict__ esrc, const int* __restrict__ edst,
            unsigned int* __restrict__ copies,      // [K][R*HWORDS]
            int* __restrict__ gene_cnt, int* __restrict__ gene_src,
            unsigned int* __restrict__ flagw,
            int e, int K, int R) {
    __shared__ unsigned int lds[HWORDS];
    const int r = blockIdx.x, k = blockIdx.y;
    const int tid = threadIdx.x;
    {
        uint4* l4 = (uint4*)lds;
        for (int w = tid; w < HWORDS / 4; w += BHIST) l4[w] = make_uint4(0, 0, 0, 0);
    }
    __syncthreads();

    const unsigned int lo = (unsigned int)r * HBINS;
    const int e4 = e >> 2;
    const int Q = (e4 + K - 1) / K;
    const int beg = k * Q;
    const int end = min(beg + Q, e4);
    const int4* ed4 = (const int4*)edst;
    const int len = (end > beg) ? (end - beg) : 0;
    const int quarter = len >> 2;

    auto proc = [&](int j, int4 d4) {
#pragma unroll
        for (int c = 0; c < 4; c++) {
            unsigned int d = (unsigned int)((&d4.x)[c]);
            unsigned int rel = d - lo;
            if (rel < HBINS)
                atomicAdd(&lds[rel >> 3], 1u << ((rel & 7u) * 4u));
            if (r == 0) {
                unsigned int graph = d / NODES;
                unsigned int pos = d - graph * NODES;
                if (pos >= GENE0) {
                    int s = esrc[4 * j + c];
                    atomicOr(&flagw[(unsigned)s >> 5], 1u << (s & 31));
                    int g = (int)(graph * NHEADS + (pos - GENE0));
                    int p = atomicAdd(gene_cnt + g, 1);
                    if (p < GMAX) gene_src[(g << 6) + p] = s;
                }
            }
        }
    };

    // four independent streams -> 4 int4 loads in flight per wave
    for (int i = tid; i < quarter; i += BHIST) {
        int j1 = beg + i;
        int j2 = j1 + quarter;
        int j3 = j2 + quarter;
        int j4 = j3 + quarter;
        int4 a = ed4[j1];
        int4 b = ed4[j2];
        int4 cc = ed4[j3];
        int4 dd = ed4[j4];
        proc(j1, a); proc(j2, b); proc(j3, cc); proc(j4, dd);
    }
    for (int i = (quarter << 2) + tid; i < len; i += BHIST) {
        int j = beg + i;
        proc(j, ed4[j]);
    }
    // tail edges (e % 4) — chunk-0 blocks of every range
    if (k == 0) {
        for (int j = (e4 << 2) + tid; j < e; j += BHIST) {
            unsigned int d = (unsigned int)edst[j];
            unsigned int rel = d - lo;
            if (rel < HBINS)
                atomicAdd(&lds[rel >> 3], 1u << ((rel & 7u) * 4u));
            if (r == 0) {
                unsigned int graph = d / NODES;
                unsigned int pos = d - graph * NODES;
                if (pos >= GENE0) {
                    int s = esrc[j];
                    atomicOr(&flagw[(unsigned)s >> 5], 1u << (s & 31));
                    int g = (int)(graph * NHEADS + (pos - GENE0));
                    int p = atomicAdd(gene_cnt + g, 1);
                    if (p < GMAX) gene_src[(g << 6) + p] = s;
                }
            }
        }
    }
    __syncthreads();
    uint4* dst4 = (uint4*)(copies + ((size_t)k * R + r) * HWORDS);
    const uint4* l4 = (const uint4*)lds;
    for (int w = tid; w < HWORDS / 4; w += BHIST) dst4[w] = l4[w];
}

// Pass 2: sum K nibble-histograms (SWAR, 4-way unroll), dinv = rsqrt(deg+1),
// zero t, set gene-node bits in the flag mask.
__global__ void k_reduce(const unsigned int* __restrict__ copies,
                         float* __restrict__ dinv, float* __restrict__ t,
                         unsigned int* __restrict__ flagw,
                         int n, int K, int Wtot) {
    int w = blockIdx.x * blockDim.x + threadIdx.x;
    if (w >= Wtot) return;
    const unsigned int M = 0x0F0F0F0Fu;
    unsigned int e0 = 0, o0 = 0, e1 = 0, o1 = 0, e2 = 0, o2 = 0, e3 = 0, o3 = 0;
    int k = 0;
    for (; k + 4 <= K; k += 4) {
        unsigned int u0 = copies[(size_t)(k + 0) * Wtot + w];
        unsigned int u1 = copies[(size_t)(k + 1) * Wtot + w];
        unsigned int u2 = copies[(size_t)(k + 2) * Wtot + w];
        unsigned int u3 = copies[(size_t)(k + 3) * Wtot + w];
        e0 += u0 & M; o0 += (u0 >> 4) & M;
        e1 += u1 & M; o1 += (u1 >> 4) & M;
        e2 += u2 & M; o2 += (u2 >> 4) & M;
        e3 += u3 & M; o3 += (u3 >> 4) & M;
    }
    for (; k < K; k++) {
        unsigned int u = copies[(size_t)k * Wtot + w];
        e0 += u & M; o0 += (u >> 4) & M;
    }
    unsigned int evn = e0 + e1 + e2 + e3;   // byte lanes: sum == node degree <= ~40
    unsigned int odd = o0 + o1 + o2 + o3;
    int i0 = w << 3;
    float v[8];
#pragma unroll
    for (int b = 0; b < 4; b++) {
        v[2 * b]     = (float)((evn >> (8 * b)) & 0xFFu);
        v[2 * b + 1] = (float)((odd >> (8 * b)) & 0xFFu);
    }
#pragma unroll
    for (int b = 0; b < 8; b++) v[b] = rsqrtf(v[b] + 1.f);
    float4 z4 = {0.f, 0.f, 0.f, 0.f};
    if (i0 + 7 < n) {
        float4 lo4 = {v[0], v[1], v[2], v[3]};
        float4 hi4 = {v[4], v[5], v[6], v[7]};
        *(float4*)(dinv + i0) = lo4;
        *(float4*)(dinv + i0 + 4) = hi4;
        *(float4*)(t + i0) = z4;
        *(float4*)(t + i0 + 4) = z4;
    } else {
        for (int b = 0; b < 8; b++)
            if (i0 + b < n) { dinv[i0 + b] = v[b]; t[i0 + b] = 0.f; }
    }
#pragma unroll
    for (int b = 0; b < 8; b++) {
        int i = i0 + b;
        if (i < n) {
            unsigned int graph = (unsigned int)i / NODES;
            unsigned int pos = (unsigned int)i - graph * NODES;
            if (pos >= GENE0) atomicOr(&flagw[(unsigned)i >> 5], 1u << (i & 31));
        }
    }
}

// Pass 3: layer-1 scatter into flagged dst only (~5.6% of edges).
// t~[d] = sum dinv[s]*x[s]  (dinv[d] factor folded into consumers).
__global__ void k_l1_scatter(const int* __restrict__ esrc, const int* __restrict__ edst,
                             const float* __restrict__ x, const float* __restrict__ dinv,
                             const unsigned int* __restrict__ flagw,
                             float* __restrict__ t, int e) {
    int q = blockIdx.x * blockDim.x + threadIdx.x;
    int e8 = e >> 3;
    if (q < e8) {
        const int4* ed4 = (const int4*)edst;
        const int4* es4 = (const int4*)esrc;
        int4 da = ed4[2 * q];
        int4 db = ed4[2 * q + 1];
        int4 sa = es4[2 * q];
        int4 sb = es4[2 * q + 1];
#pragma unroll
        for (int c = 0; c < 4; c++) {
            int d = (&da.x)[c];
            if ((flagw[(unsigned)d >> 5] >> (d & 31)) & 1u) {
                int s = (&sa.x)[c];
                atomicAdd(t + d, dinv[s] * x[s]);
            }
        }
#pragma unroll
        for (int c = 0; c < 4; c++) {
            int d = (&db.x)[c];
            if ((flagw[(unsigned)d >> 5] >> (d & 31)) & 1u) {
                int s = (&sb.x)[c];
                atomicAdd(t + d, dinv[s] * x[s]);
            }
        }
    } else if (q == e8) {
        for (int j = e8 << 3; j < e; j++) {
            int d = edst[j];
            if (!((flagw[(unsigned)d >> 5] >> (d & 31)) & 1u)) continue;
            int s = esrc[j];
            atomicAdd(t + d, dinv[s] * x[s]);
        }
    }
}

// Pass 4 (fused): one WAVE per gene. Lane i handles bucketed edge i,
// butterfly-reduce, lane 0 finalizes + per-head 16->8->1 MLP.
// u[v] = dinv[v]*(t~[v] + dinv[v]*x[v]).
__global__ void k_gene_final(const int* __restrict__ gene_cnt, const int* __restrict__ gene_src,
                             const float* __restrict__ t, const float* __restrict__ dinv,
                             const float* __restrict__ x,
                             const float* __restrict__ W1, const float* __restrict__ b1,
                             const float* __restrict__ W2, const float* __restrict__ b2,
                             const float* __restrict__ fw1, const float* __restrict__ fb1,
                             const float* __restrict__ fw2, const float* __restrict__ fb2,
                             float* __restrict__ out, int NG, int G) {
    int wid = (blockIdx.x * blockDim.x + threadIdx.x) >> 6;
    int lane = threadIdx.x & 63;
    if (wid >= NG) return;
    int g = wid;
    int graph = g / NHEADS;
    int head = g - graph * NHEADS;
    int node = graph * NODES + GENE0 + head;
    int cnt = min(gene_cnt[g], GMAX);

    float contrib[16];
#pragma unroll
    for (int c = 0; c < 16; c++) contrib[c] = 0.f;
    if (lane < cnt) {
        int s = gene_src[(g << 6) + lane];
        float ds = dinv[s];
        float us = ds * (t[s] + ds * x[s]);
        float l1[16];
#pragma unroll
        for (int kk = 0; kk < 16; kk++) l1[kk] = frelu(us * W1[kk] + b1[kk]);
#pragma unroll
        for (int c = 0; c < 16; c++) {
            float m = 0.f;
#pragma unroll
            for (int kk = 0; kk < 16; kk++) m += l1[kk] * W2[kk * 16 + c];
            contrib[c] = ds * m;
        }
    }
#pragma unroll
    for (int off = 32; off > 0; off >>= 1) {
#pragma unroll
        for (int c = 0; c < 16; c++)
            contrib[c] += __shfl_xor(contrib[c], off, 64);
    }
    if (lane == 0) {
        float dn = dinv[node];
        float un = dn * (t[node] + dn * x[node]);
        float l1[16];
#pragma unroll
        for (int kk = 0; kk < 16; kk++) l1[kk] = frelu(un * W1[kk] + b1[kk]);
        float dsq = dn * dn;
        float h[16];
#pragma unroll
        for (int c = 0; c < 16; c++) {
            float h2 = 0.f;
#pragma unroll
            for (int kk = 0; kk < 16; kk++) h2 += l1[kk] * W2[kk * 16 + c];
            h[c] = frelu(dn * contrib[c] + dsq * h2 + b2[c]);
        }
        float pred = fb2[head];
#pragma unroll
        for (int kk = 0; kk < 8; kk++) {
            float z = fb1[head * 8 + kk];
#pragma unroll
            for (int c = 0; c < 16; c++) z += h[c] * fw1[head * 128 + c * 8 + kk];
            pred += frelu(z) * fw2[head * 8 + kk];
        }
        out[head * G + graph] = pred;
    }
}

extern "C" void kernel_launch(void* const* d_in, const int* in_sizes, int n_in,
                              void* d_out, int out_size, void* d_ws, size_t ws_size,
                              hipStream_t stream) {
    const float* x   = (const float*)d_in[0];
    const int*   ei  = (const int*)d_in[1];
    const float* W1  = (const float*)d_in[3];
    const float* b1  = (const float*)d_in[4];
    const float* W2  = (const float*)d_in[5];
    const float* b2  = (const float*)d_in[6];
    const float* fw1 = (const float*)d_in[7];
    const float* fb1 = (const float*)d_in[8];
    const float* fw2 = (const float*)d_in[9];
    const float* fb2 = (const float*)d_in[10];

    int n = in_sizes[0];
    int e = in_sizes[1] / 2;
    int G = in_sizes[2] / NHEADS;
    int NG = G * NHEADS;
    const int* esrc = ei;
    const int* edst = ei + e;

    char* ws = (char*)d_ws;
    size_t off = 0;
    auto alloc = [&](size_t bytes) {
        char* p = ws + off;
        off += (bytes + 255) & ~(size_t)255;
        return p;
    };
    // zero-init region (small): gene counters + flag bitmask
    int*   gene_cnt      = (int*)alloc((size_t)NG * 4);
    unsigned int* flagw  = (unsigned int*)alloc((size_t)((n + 31) / 32) * 4);
    size_t zero_bytes    = off;
    // written-before-read region
    float* t             = (float*)alloc((size_t)n * 4);   // zeroed by k_reduce
    float* dinv          = (float*)alloc((size_t)n * 4);
    int*   gene_src      = (int*)alloc((size_t)NG * GMAX * 4);
    size_t fixed         = off;

    int R = (n + HBINS - 1) / HBINS;                  // 6 for n=732160
    size_t per_copy = (size_t)R * HWORDS * 4;         // 384 KB per chunk
    int K = 64;                                       // grid 6x64=384 blocks; copies 25 MB
    if (fixed + (size_t)K * per_copy > ws_size) {
        size_t avail = (ws_size > fixed) ? (ws_size - fixed) : 0;
        int kfit = (int)(avail / per_copy);
        K = kfit < 1 ? 1 : (kfit < K ? kfit : K);
    }
    unsigned int* copies = (unsigned int*)alloc((size_t)K * per_copy);
    (void)n_in; (void)out_size;

    hipMemsetAsync(d_ws, 0, zero_bytes, stream);

    const int B = 256;
    k_hist<<<dim3(R, K), BHIST, 0, stream>>>(esrc, edst, copies, gene_cnt, gene_src,
                                             flagw, e, K, R);
    int Wtot = R * HWORDS;
    k_reduce<<<(Wtot + B - 1) / B, B, 0, stream>>>(copies, dinv, t, flagw, n, K, Wtot);
    int e8b = (e >> 3) + 1;
    k_l1_scatter<<<(e8b + B - 1) / B, B, 0, stream>>>(esrc, edst, x, dinv, flagw, t, e);
    int waves_blocks = (NG * 64 + B - 1) / B;
    k_gene_final<<<waves_blocks, B, 0, stream>>>(gene_cnt, gene_src, t, dinv, x,
                                                 W1, b1, W2, b2,
                                                 fw1, fb1, fw2, fb2,
                                                 (float*)d_out, NG, G);
}

// Round 8
// 213.587 us; speedup vs baseline: 3.0509x; 1.0580x over previous
//
#include <hip/hip_runtime.h>

#define NODES 1430
#define GENE0 1421
#define NHEADS 9
#define HBINS 131072         // bins per block; 4-bit counts, 8 per u32
#define HWORDS (HBINS / 8)   // 16384 u32 words = 64 KB LDS (gfx9 per-WG max)
#define BHIST 1024           // 16 waves/block; 2 blocks/CU thread-cap
#define GMAX 64              // max bucketed in-edges per gene (Poisson(8) tail ~0)

__device__ __forceinline__ float frelu(float v) { return v > 0.f ? v : 0.f; }

// Pass 1: privatized LDS histogram (4-bit packed) of in-degree.
// 1-D grid of K*R blocks, XCD-swizzled: all R range-blocks of one edge chunk
// land on the SAME XCD (id%8 assumption) so the chunk is HBM-read once and
// L2-served for the other R-1 ranges. r==0 blocks also bucket gene-dst edges.
__global__ __launch_bounds__(BHIST, 4)
void k_hist(const int* __restrict__ esrc, const int* __restrict__ edst,
            unsigned int* __restrict__ copies,      // [K][R*HWORDS]
            int* __restrict__ gene_cnt, int* __restrict__ gene_src,
            unsigned int* __restrict__ flagw,
            int e, int K, int R) {
    __shared__ unsigned int lds[HWORDS];
    int id = blockIdx.x;
    int k, r;
    if ((K & 7) == 0) {
        int xcd = id & 7;
        int slot = id >> 3;
        int cin = slot / R;          // chunk index within this XCD
        k = xcd * (K >> 3) + cin;
        r = slot - cin * R;
    } else {
        k = id / R;
        r = id - k * R;
    }
    const int tid = threadIdx.x;
    {
        uint4* l4 = (uint4*)lds;
        for (int w = tid; w < HWORDS / 4; w += BHIST) l4[w] = make_uint4(0, 0, 0, 0);
    }
    __syncthreads();

    const unsigned int lo = (unsigned int)r * HBINS;
    const int e4 = e >> 2;
    const int Q = (e4 + K - 1) / K;
    const int beg = k * Q;
    const int end = min(beg + Q, e4);
    const int4* ed4 = (const int4*)edst;
    const int len = (end > beg) ? (end - beg) : 0;
    const int quarter = len >> 2;

    auto proc = [&](int j, int4 d4) {
#pragma unroll
        for (int c = 0; c < 4; c++) {
            unsigned int d = (unsigned int)((&d4.x)[c]);
            unsigned int rel = d - lo;
            if (rel < HBINS)
                atomicAdd(&lds[rel >> 3], 1u << ((rel & 7u) * 4u));
            if (r == 0) {
                unsigned int graph = d / NODES;
                unsigned int pos = d - graph * NODES;
                if (pos >= GENE0) {
                    int s = esrc[4 * j + c];
                    atomicOr(&flagw[(unsigned)s >> 5], 1u << (s & 31));
                    int g = (int)(graph * NHEADS + (pos - GENE0));
                    int p = atomicAdd(gene_cnt + g, 1);
                    if (p < GMAX) gene_src[(g << 6) + p] = s;
                }
            }
        }
    };

    // four independent streams -> 4 int4 loads in flight per wave
    for (int i = tid; i < quarter; i += BHIST) {
        int j1 = beg + i;
        int j2 = j1 + quarter;
        int j3 = j2 + quarter;
        int j4 = j3 + quarter;
        int4 a = ed4[j1];
        int4 b = ed4[j2];
        int4 cc = ed4[j3];
        int4 dd = ed4[j4];
        proc(j1, a); proc(j2, b); proc(j3, cc); proc(j4, dd);
    }
    for (int i = (quarter << 2) + tid; i < len; i += BHIST) {
        int j = beg + i;
        proc(j, ed4[j]);
    }
    // tail edges (e % 4) — chunk-0 blocks of every range
    if (k == 0) {
        for (int j = (e4 << 2) + tid; j < e; j += BHIST) {
            unsigned int d = (unsigned int)edst[j];
            unsigned int rel = d - lo;
            if (rel < HBINS)
                atomicAdd(&lds[rel >> 3], 1u << ((rel & 7u) * 4u));
            if (r == 0) {
                unsigned int graph = d / NODES;
                unsigned int pos = d - graph * NODES;
                if (pos >= GENE0) {
                    int s = esrc[j];
                    atomicOr(&flagw[(unsigned)s >> 5], 1u << (s & 31));
                    int g = (int)(graph * NHEADS + (pos - GENE0));
                    int p = atomicAdd(gene_cnt + g, 1);
                    if (p < GMAX) gene_src[(g << 6) + p] = s;
                }
            }
        }
    }
    __syncthreads();
    uint4* dst4 = (uint4*)(copies + ((size_t)k * R + r) * HWORDS);
    const uint4* l4 = (const uint4*)lds;
    for (int w = tid; w < HWORDS / 4; w += BHIST) dst4[w] = l4[w];
}

// Pass 2: sum K nibble-histograms (SWAR, 4-way unroll). Writes
// dx[i] = {dinv, dinv*x}, zeroes t, sets gene-node flag bits.
__global__ void k_reduce(const unsigned int* __restrict__ copies,
                         const float* __restrict__ x,
                         float2* __restrict__ dx, float* __restrict__ t,
                         unsigned int* __restrict__ flagw,
                         int n, int K, int Wtot) {
    int w = blockIdx.x * blockDim.x + threadIdx.x;
    if (w >= Wtot) return;
    const unsigned int M = 0x0F0F0F0Fu;
    unsigned int e0 = 0, o0 = 0, e1 = 0, o1 = 0, e2 = 0, o2 = 0, e3 = 0, o3 = 0;
    int k = 0;
    for (; k + 4 <= K; k += 4) {
        unsigned int u0 = copies[(size_t)(k + 0) * Wtot + w];
        unsigned int u1 = copies[(size_t)(k + 1) * Wtot + w];
        unsigned int u2 = copies[(size_t)(k + 2) * Wtot + w];
        unsigned int u3 = copies[(size_t)(k + 3) * Wtot + w];
        e0 += u0 & M; o0 += (u0 >> 4) & M;
        e1 += u1 & M; o1 += (u1 >> 4) & M;
        e2 += u2 & M; o2 += (u2 >> 4) & M;
        e3 += u3 & M; o3 += (u3 >> 4) & M;
    }
    for (; k < K; k++) {
        unsigned int u = copies[(size_t)k * Wtot + w];
        e0 += u & M; o0 += (u >> 4) & M;
    }
    unsigned int evn = e0 + e1 + e2 + e3;   // byte lanes: sum == node degree <= 255
    unsigned int odd = o0 + o1 + o2 + o3;
    int i0 = w << 3;
    float v[8];
#pragma unroll
    for (int b = 0; b < 4; b++) {
        v[2 * b]     = (float)((evn >> (8 * b)) & 0xFFu);
        v[2 * b + 1] = (float)((odd >> (8 * b)) & 0xFFu);
    }
#pragma unroll
    for (int b = 0; b < 8; b++) v[b] = rsqrtf(v[b] + 1.f);
    float4 z4 = {0.f, 0.f, 0.f, 0.f};
    if (i0 + 7 < n) {
        float4 xa = *(const float4*)(x + i0);
        float4 xb = *(const float4*)(x + i0 + 4);
        float4 p0 = {v[0], v[0] * xa.x, v[1], v[1] * xa.y};
        float4 p1 = {v[2], v[2] * xa.z, v[3], v[3] * xa.w};
        float4 p2 = {v[4], v[4] * xb.x, v[5], v[5] * xb.y};
        float4 p3 = {v[6], v[6] * xb.z, v[7], v[7] * xb.w};
        float4* dst = (float4*)(dx + i0);
        dst[0] = p0; dst[1] = p1; dst[2] = p2; dst[3] = p3;
        *(float4*)(t + i0) = z4;
        *(float4*)(t + i0 + 4) = z4;
    } else {
        for (int b = 0; b < 8; b++)
            if (i0 + b < n) {
                float xv = x[i0 + b];
                dx[i0 + b] = make_float2(v[b], v[b] * xv);
                t[i0 + b] = 0.f;
            }
    }
#pragma unroll
    for (int b = 0; b < 8; b++) {
        int i = i0 + b;
        if (i < n) {
            unsigned int graph = (unsigned int)i / NODES;
            unsigned int pos = (unsigned int)i - graph * NODES;
            if (pos >= GENE0) atomicOr(&flagw[(unsigned)i >> 5], 1u << (i & 31));
        }
    }
}

// Pass 3: layer-1 scatter into flagged dst only (~5.6% of edges).
// t~[d] += dinv[s]*x[s] == dx[s].y — one 8B gather per hit.
__global__ void k_l1_scatter(const int* __restrict__ esrc, const int* __restrict__ edst,
                             const float2* __restrict__ dx,
                             const unsigned int* __restrict__ flagw,
                             float* __restrict__ t, int e) {
    int q = blockIdx.x * blockDim.x + threadIdx.x;
    int e8 = e >> 3;
    if (q < e8) {
        const int4* ed4 = (const int4*)edst;
        const int4* es4 = (const int4*)esrc;
        int4 da = ed4[2 * q];
        int4 db = ed4[2 * q + 1];
        int4 sa = es4[2 * q];
        int4 sb = es4[2 * q + 1];
#pragma unroll
        for (int c = 0; c < 4; c++) {
            int d = (&da.x)[c];
            if ((flagw[(unsigned)d >> 5] >> (d & 31)) & 1u) {
                int s = (&sa.x)[c];
                atomicAdd(t + d, dx[s].y);
            }
        }
#pragma unroll
        for (int c = 0; c < 4; c++) {
            int d = (&db.x)[c];
            if ((flagw[(unsigned)d >> 5] >> (d & 31)) & 1u) {
                int s = (&sb.x)[c];
                atomicAdd(t + d, dx[s].y);
            }
        }
    } else if (q == e8) {
        for (int j = e8 << 3; j < e; j++) {
            int d = edst[j];
            if (!((flagw[(unsigned)d >> 5] >> (d & 31)) & 1u)) continue;
            int s = esrc[j];
            atomicAdd(t + d, dx[s].y);
        }
    }
}

// Pass 4 (fused): one WAVE per gene. Lane i handles bucketed edge i,
// butterfly-reduce, lane 0 finalizes + per-head 16->8->1 MLP.
// u[v] = dinv*t~ + dinv*(dinv*x) = dx.x*t + dx.x*dx.y.
__global__ void k_gene_final(const int* __restrict__ gene_cnt, const int* __restrict__ gene_src,
                             const float* __restrict__ t, const float2* __restrict__ dx,
                             const float* __restrict__ W1, const float* __restrict__ b1,
                             const float* __restrict__ W2, const float* __restrict__ b2,
                             const float* __restrict__ fw1, const float* __restrict__ fb1,
                             const float* __restrict__ fw2, const float* __restrict__ fb2,
                             float* __restrict__ out, int NG, int G) {
    int wid = (blockIdx.x * blockDim.x + threadIdx.x) >> 6;
    int lane = threadIdx.x & 63;
    if (wid >= NG) return;
    int g = wid;
    int graph = g / NHEADS;
    int head = g - graph * NHEADS;
    int node = graph * NODES + GENE0 + head;
    int cnt = min(gene_cnt[g], GMAX);

    float contrib[16];
#pragma unroll
    for (int c = 0; c < 16; c++) contrib[c] = 0.f;
    if (lane < cnt) {
        int s = gene_src[(g << 6) + lane];
        float2 ds2 = dx[s];
        float ds = ds2.x;
        float us = ds * t[s] + ds * ds2.y;
        float l1[16];
#pragma unroll
        for (int kk = 0; kk < 16; kk++) l1[kk] = frelu(us * W1[kk] + b1[kk]);
#pragma unroll
        for (int c = 0; c < 16; c++) {
            float m = 0.f;
#pragma unroll
            for (int kk = 0; kk < 16; kk++) m += l1[kk] * W2[kk * 16 + c];
            contrib[c] = ds * m;
        }
    }
#pragma unroll
    for (int off = 32; off > 0; off >>= 1) {
#pragma unroll
        for (int c = 0; c < 16; c++)
            contrib[c] += __shfl_xor(contrib[c], off, 64);
    }
    if (lane == 0) {
        float2 dn2 = dx[node];
        float dn = dn2.x;
        float un = dn * t[node] + dn * dn2.y;
        float l1[16];
#pragma unroll
        for (int kk = 0; kk < 16; kk++) l1[kk] = frelu(un * W1[kk] + b1[kk]);
        float dsq = dn * dn;
        float h[16];
#pragma unroll
        for (int c = 0; c < 16; c++) {
            float h2 = 0.f;
#pragma unroll
            for (int kk = 0; kk < 16; kk++) h2 += l1[kk] * W2[kk * 16 + c];
            h[c] = frelu(dn * contrib[c] + dsq * h2 + b2[c]);
        }
        float pred = fb2[head];
#pragma unroll
        for (int kk = 0; kk < 8; kk++) {
            float z = fb1[head * 8 + kk];
#pragma unroll
            for (int c = 0; c < 16; c++) z += h[c] * fw1[head * 128 + c * 8 + kk];
            pred += frelu(z) * fw2[head * 8 + kk];
        }
        out[head * G + graph] = pred;
    }
}

extern "C" void kernel_launch(void* const* d_in, const int* in_sizes, int n_in,
                              void* d_out, int out_size, void* d_ws, size_t ws_size,
                              hipStream_t stream) {
    const float* x   = (const float*)d_in[0];
    const int*   ei  = (const int*)d_in[1];
    const float* W1  = (const float*)d_in[3];
    const float* b1  = (const float*)d_in[4];
    const float* W2  = (const float*)d_in[5];
    const float* b2  = (const float*)d_in[6];
    const float* fw1 = (const float*)d_in[7];
    const float* fb1 = (const float*)d_in[8];
    const float* fw2 = (const float*)d_in[9];
    const float* fb2 = (const float*)d_in[10];

    int n = in_sizes[0];
    int e = in_sizes[1] / 2;
    int G = in_sizes[2] / NHEADS;
    int NG = G * NHEADS;
    const int* esrc = ei;
    const int* edst = ei + e;

    char* ws = (char*)d_ws;
    size_t off = 0;
    auto alloc = [&](size_t bytes) {
        char* p = ws + off;
        off += (bytes + 255) & ~(size_t)255;
        return p;
    };
    // zero-init region (small): gene counters + flag bitmask
    int*   gene_cnt      = (int*)alloc((size_t)NG * 4);
    unsigned int* flagw  = (unsigned int*)alloc((size_t)((n + 31) / 32) * 4);
    size_t zero_bytes    = off;
    // written-before-read region
    float*  t            = (float*)alloc((size_t)n * 4);       // zeroed by k_reduce
    float2* dx           = (float2*)alloc((size_t)n * 8);      // {dinv, dinv*x}
    int*    gene_src     = (int*)alloc((size_t)NG * GMAX * 4);
    size_t fixed         = off;

    int R = (n + HBINS - 1) / HBINS;                  // 6 for n=732160
    size_t per_copy = (size_t)R * HWORDS * 4;         // 384 KB per chunk
    int K = 80;                                       // mult of 8; 480 blocks ~ 512 slots
    if (fixed + (size_t)K * per_copy > ws_size) {
        size_t avail = (ws_size > fixed) ? (ws_size - fixed) : 0;
        int kfit = (int)(avail / per_copy);
        if (kfit >= 8) kfit &= ~7;                    // keep multiple of 8 for swizzle
        K = kfit < 1 ? 1 : (kfit < K ? kfit : K);
    }
    unsigned int* copies = (unsigned int*)alloc((size_t)K * per_copy);
    (void)n_in; (void)out_size;

    hipMemsetAsync(d_ws, 0, zero_bytes, stream);

    const int B = 256;
    k_hist<<<K * R, BHIST, 0, stream>>>(esrc, edst, copies, gene_cnt, gene_src,
                                        flagw, e, K, R);
    int Wtot = R * HWORDS;
    k_reduce<<<(Wtot + B - 1) / B, B, 0, stream>>>(copies, x, dx, t, flagw, n, K, Wtot);
    int e8b = (e >> 3) + 1;
    k_l1_scatter<<<(e8b + B - 1) / B, B, 0, stream>>>(esrc, edst, dx, flagw, t, e);
    int waves_blocks = (NG * 64 + B - 1) / B;
    k_gene_final<<<waves_blocks, B, 0, stream>>>(gene_cnt, gene_src, t, dx,
                                                 W1, b1, W2, b2,
                                                 fw1, fb1, fw2, fb2,
                                                 (float*)d_out, NG, G);
}

// Round 9
// 200.473 us; speedup vs baseline: 3.2505x; 1.0654x over previous
//
#include <hip/hip_runtime.h>

#define NODES 1430
#define GENE0 1421
#define NHEADS 9
#define HBINS 131072         // bins per block; 4-bit counts, 8 per u32
#define HWORDS (HBINS / 8)   // 16384 u32 words = 64 KB LDS (gfx9 per-WG max)
#define BHIST 1024           // 16 waves/block; 2 blocks/CU thread-cap
#define GMAX 64              // max bucketed in-edges per gene (Poisson(8) tail ~0)

__device__ __forceinline__ float frelu(float v) { return v > 0.f ? v : 0.f; }

// Pass 1: privatized LDS histogram (4-bit packed) of in-degree.
// 1-D grid of K*R blocks, XCD-swizzled: all R range-blocks of one edge chunk
// land on the SAME XCD (confirmed R8: FETCH 71->20 MB) so the chunk is
// HBM-read once and L2-served for the other R-1 ranges.
// Gene-detection is distributed: block (k,r) gene-scans the r-th sub-slice
// of the chunk, so all blocks carry identical work (no r==0 straggler tail).
__global__ __launch_bounds__(BHIST, 4)
void k_hist(const int* __restrict__ esrc, const int* __restrict__ edst,
            unsigned int* __restrict__ copies,      // [K][R*HWORDS]
            int* __restrict__ gene_cnt, int* __restrict__ gene_src,
            unsigned int* __restrict__ flagw,
            int e, int K, int R) {
    __shared__ unsigned int lds[HWORDS];
    int id = blockIdx.x;
    int k, r;
    if ((K & 7) == 0) {
        int xcd = id & 7;
        int slot = id >> 3;
        int cin = slot / R;          // chunk index within this XCD
        k = xcd * (K >> 3) + cin;
        r = slot - cin * R;
    } else {
        k = id / R;
        r = id - k * R;
    }
    const int tid = threadIdx.x;
    {
        uint4* l4 = (uint4*)lds;
        for (int w = tid; w < HWORDS / 4; w += BHIST) l4[w] = make_uint4(0, 0, 0, 0);
    }
    __syncthreads();

    const unsigned int lo = (unsigned int)r * HBINS;
    const int e4 = e >> 2;
    const int Q = (e4 + K - 1) / K;
    const int beg = k * Q;
    const int end = min(beg + Q, e4);
    const int4* ed4 = (const int4*)edst;
    const int len = (end > beg) ? (end - beg) : 0;
    const int quarter = len >> 2;

    // histogram-only edge decode (no gene work in the hot loop)
    auto proc = [&](int4 d4) {
#pragma unroll
        for (int c = 0; c < 4; c++) {
            unsigned int d = (unsigned int)((&d4.x)[c]);
            unsigned int rel = d - lo;
            if (rel < HBINS)
                atomicAdd(&lds[rel >> 3], 1u << ((rel & 7u) * 4u));
        }
    };

    // four independent streams -> 4 int4 loads in flight per wave
    for (int i = tid; i < quarter; i += BHIST) {
        int j1 = beg + i;
        int j2 = j1 + quarter;
        int j3 = j2 + quarter;
        int j4 = j3 + quarter;
        int4 a = ed4[j1];
        int4 b = ed4[j2];
        int4 cc = ed4[j3];
        int4 dd = ed4[j4];
        proc(a); proc(b); proc(cc); proc(dd);
    }
    for (int i = (quarter << 2) + tid; i < len; i += BHIST) {
        proc(ed4[beg + i]);
    }

    // gene-scan: this block's sub-slice of the chunk (edges are L2-hot).
    {
        int sbeg = beg + (int)(((long long)len * r) / R);
        int send = beg + (int)(((long long)len * (r + 1)) / R);
        for (int j = sbeg + tid; j < send; j += BHIST) {
            int4 d4 = ed4[j];
#pragma unroll
            for (int c = 0; c < 4; c++) {
                unsigned int d = (unsigned int)((&d4.x)[c]);
                unsigned int graph = d / NODES;
                unsigned int pos = d - graph * NODES;
                if (pos >= GENE0) {
                    int s = esrc[4 * j + c];
                    atomicOr(&flagw[(unsigned)s >> 5], 1u << (s & 31));
                    int g = (int)(graph * NHEADS + (pos - GENE0));
                    int p = atomicAdd(gene_cnt + g, 1);
                    if (p < GMAX) gene_src[(g << 6) + p] = s;
                }
            }
        }
    }

    // tail edges (e % 4) — k==0 blocks: every range does hist, r==0 does genes
    if (k == 0) {
        for (int j = (e4 << 2) + tid; j < e; j += BHIST) {
            unsigned int d = (unsigned int)edst[j];
            unsigned int rel = d - lo;
            if (rel < HBINS)
                atomicAdd(&lds[rel >> 3], 1u << ((rel & 7u) * 4u));
            if (r == 0) {
                unsigned int graph = d / NODES;
                unsigned int pos = d - graph * NODES;
                if (pos >= GENE0) {
                    int s = esrc[j];
                    atomicOr(&flagw[(unsigned)s >> 5], 1u << (s & 31));
                    int g = (int)(graph * NHEADS + (pos - GENE0));
                    int p = atomicAdd(gene_cnt + g, 1);
                    if (p < GMAX) gene_src[(g << 6) + p] = s;
                }
            }
        }
    }
    __syncthreads();
    uint4* dst4 = (uint4*)(copies + ((size_t)k * R + r) * HWORDS);
    const uint4* l4 = (const uint4*)lds;
    for (int w = tid; w < HWORDS / 4; w += BHIST) dst4[w] = l4[w];
}

// Pass 2: sum K nibble-histograms (SWAR, 4-way unroll). Writes
// dx[i] = {dinv, dinv*x}, zeroes t, sets gene-node flag bits.
__global__ void k_reduce(const unsigned int* __restrict__ copies,
                         const float* __restrict__ x,
                         float2* __restrict__ dx, float* __restrict__ t,
                         unsigned int* __restrict__ flagw,
                         int n, int K, int Wtot) {
    int w = blockIdx.x * blockDim.x + threadIdx.x;
    if (w >= Wtot) return;
    const unsigned int M = 0x0F0F0F0Fu;
    unsigned int e0 = 0, o0 = 0, e1 = 0, o1 = 0, e2 = 0, o2 = 0, e3 = 0, o3 = 0;
    int k = 0;
    for (; k + 4 <= K; k += 4) {
        unsigned int u0 = copies[(size_t)(k + 0) * Wtot + w];
        unsigned int u1 = copies[(size_t)(k + 1) * Wtot + w];
        unsigned int u2 = copies[(size_t)(k + 2) * Wtot + w];
        unsigned int u3 = copies[(size_t)(k + 3) * Wtot + w];
        e0 += u0 & M; o0 += (u0 >> 4) & M;
        e1 += u1 & M; o1 += (u1 >> 4) & M;
        e2 += u2 & M; o2 += (u2 >> 4) & M;
        e3 += u3 & M; o3 += (u3 >> 4) & M;
    }
    for (; k < K; k++) {
        unsigned int u = copies[(size_t)k * Wtot + w];
        e0 += u & M; o0 += (u >> 4) & M;
    }
    unsigned int evn = e0 + e1 + e2 + e3;   // byte lanes: sum == node degree <= 255
    unsigned int odd = o0 + o1 + o2 + o3;
    int i0 = w << 3;
    float v[8];
#pragma unroll
    for (int b = 0; b < 4; b++) {
        v[2 * b]     = (float)((evn >> (8 * b)) & 0xFFu);
        v[2 * b + 1] = (float)((odd >> (8 * b)) & 0xFFu);
    }
#pragma unroll
    for (int b = 0; b < 8; b++) v[b] = rsqrtf(v[b] + 1.f);
    float4 z4 = {0.f, 0.f, 0.f, 0.f};
    if (i0 + 7 < n) {
        float4 xa = *(const float4*)(x + i0);
        float4 xb = *(const float4*)(x + i0 + 4);
        float4 p0 = {v[0], v[0] * xa.x, v[1], v[1] * xa.y};
        float4 p1 = {v[2], v[2] * xa.z, v[3], v[3] * xa.w};
        float4 p2 = {v[4], v[4] * xb.x, v[5], v[5] * xb.y};
        float4 p3 = {v[6], v[6] * xb.z, v[7], v[7] * xb.w};
        float4* dst = (float4*)(dx + i0);
        dst[0] = p0; dst[1] = p1; dst[2] = p2; dst[3] = p3;
        *(float4*)(t + i0) = z4;
        *(float4*)(t + i0 + 4) = z4;
    } else {
        for (int b = 0; b < 8; b++)
            if (i0 + b < n) {
                float xv = x[i0 + b];
                dx[i0 + b] = make_float2(v[b], v[b] * xv);
                t[i0 + b] = 0.f;
            }
    }
#pragma unroll
    for (int b = 0; b < 8; b++) {
        int i = i0 + b;
        if (i < n) {
            unsigned int graph = (unsigned int)i / NODES;
            unsigned int pos = (unsigned int)i - graph * NODES;
            if (pos >= GENE0) atomicOr(&flagw[(unsigned)i >> 5], 1u << (i & 31));
        }
    }
}

// Pass 3: layer-1 scatter into flagged dst only (~5.6% of edges).
// 16 edges/thread (4 independent int4 pairs in flight).
// t~[d] += dinv[s]*x[s] == dx[s].y — one 8B gather per hit.
__global__ void k_l1_scatter(const int* __restrict__ esrc, const int* __restrict__ edst,
                             const float2* __restrict__ dx,
                             const unsigned int* __restrict__ flagw,
                             float* __restrict__ t, int e) {
    int q = blockIdx.x * blockDim.x + threadIdx.x;
    int e16 = e >> 4;
    if (q < e16) {
        const int4* ed4 = (const int4*)edst;
        const int4* es4 = (const int4*)esrc;
        int4 d0 = ed4[4 * q + 0];
        int4 d1 = ed4[4 * q + 1];
        int4 d2 = ed4[4 * q + 2];
        int4 d3 = ed4[4 * q + 3];
        int4 s0 = es4[4 * q + 0];
        int4 s1 = es4[4 * q + 1];
        int4 s2 = es4[4 * q + 2];
        int4 s3 = es4[4 * q + 3];
        auto scat = [&](int4 dd, int4 ss) {
#pragma unroll
            for (int c = 0; c < 4; c++) {
                int d = (&dd.x)[c];
                if ((flagw[(unsigned)d >> 5] >> (d & 31)) & 1u) {
                    int s = (&ss.x)[c];
                    atomicAdd(t + d, dx[s].y);
                }
            }
        };
        scat(d0, s0); scat(d1, s1); scat(d2, s2); scat(d3, s3);
    } else if (q == e16) {
        for (int j = e16 << 4; j < e; j++) {
            int d = edst[j];
            if (!((flagw[(unsigned)d >> 5] >> (d & 31)) & 1u)) continue;
            int s = esrc[j];
            atomicAdd(t + d, dx[s].y);
        }
    }
}

// Pass 4 (fused): one WAVE per gene. Lane i handles bucketed edge i,
// butterfly-reduce, lane 0 finalizes + per-head 16->8->1 MLP.
// u[v] = dinv*t~ + dinv*(dinv*x) = dx.x*t + dx.x*dx.y.
__global__ void k_gene_final(const int* __restrict__ gene_cnt, const int* __restrict__ gene_src,
                             const float* __restrict__ t, const float2* __restrict__ dx,
                             const float* __restrict__ W1, const float* __restrict__ b1,
                             const float* __restrict__ W2, const float* __restrict__ b2,
                             const float* __restrict__ fw1, const float* __restrict__ fb1,
                             const float* __restrict__ fw2, const float* __restrict__ fb2,
                             float* __restrict__ out, int NG, int G) {
    int wid = (blockIdx.x * blockDim.x + threadIdx.x) >> 6;
    int lane = threadIdx.x & 63;
    if (wid >= NG) return;
    int g = wid;
    int graph = g / NHEADS;
    int head = g - graph * NHEADS;
    int node = graph * NODES + GENE0 + head;
    int cnt = min(gene_cnt[g], GMAX);

    float contrib[16];
#pragma unroll
    for (int c = 0; c < 16; c++) contrib[c] = 0.f;
    if (lane < cnt) {
        int s = gene_src[(g << 6) + lane];
        float2 ds2 = dx[s];
        float ds = ds2.x;
        float us = ds * t[s] + ds * ds2.y;
        float l1[16];
#pragma unroll
        for (int kk = 0; kk < 16; kk++) l1[kk] = frelu(us * W1[kk] + b1[kk]);
#pragma unroll
        for (int c = 0; c < 16; c++) {
            float m = 0.f;
#pragma unroll
            for (int kk = 0; kk < 16; kk++) m += l1[kk] * W2[kk * 16 + c];
            contrib[c] = ds * m;
        }
    }
#pragma unroll
    for (int off = 32; off > 0; off >>= 1) {
#pragma unroll
        for (int c = 0; c < 16; c++)
            contrib[c] += __shfl_xor(contrib[c], off, 64);
    }
    if (lane == 0) {
        float2 dn2 = dx[node];
        float dn = dn2.x;
        float un = dn * t[node] + dn * dn2.y;
        float l1[16];
#pragma unroll
        for (int kk = 0; kk < 16; kk++) l1[kk] = frelu(un * W1[kk] + b1[kk]);
        float dsq = dn * dn;
        float h[16];
#pragma unroll
        for (int c = 0; c < 16; c++) {
            float h2 = 0.f;
#pragma unroll
            for (int kk = 0; kk < 16; kk++) h2 += l1[kk] * W2[kk * 16 + c];
            h[c] = frelu(dn * contrib[c] + dsq * h2 + b2[c]);
        }
        float pred = fb2[head];
#pragma unroll
        for (int kk = 0; kk < 8; kk++) {
            float z = fb1[head * 8 + kk];
#pragma unroll
            for (int c = 0; c < 16; c++) z += h[c] * fw1[head * 128 + c * 8 + kk];
            pred += frelu(z) * fw2[head * 8 + kk];
        }
        out[head * G + graph] = pred;
    }
}

extern "C" void kernel_launch(void* const* d_in, const int* in_sizes, int n_in,
                              void* d_out, int out_size, void* d_ws, size_t ws_size,
                              hipStream_t stream) {
    const float* x   = (const float*)d_in[0];
    const int*   ei  = (const int*)d_in[1];
    const float* W1  = (const float*)d_in[3];
    const float* b1  = (const float*)d_in[4];
    const float* W2  = (const float*)d_in[5];
    const float* b2  = (const float*)d_in[6];
    const float* fw1 = (const float*)d_in[7];
    const float* fb1 = (const float*)d_in[8];
    const float* fw2 = (const float*)d_in[9];
    const float* fb2 = (const float*)d_in[10];

    int n = in_sizes[0];
    int e = in_sizes[1] / 2;
    int G = in_sizes[2] / NHEADS;
    int NG = G * NHEADS;
    const int* esrc = ei;
    const int* edst = ei + e;

    char* ws = (char*)d_ws;
    size_t off = 0;
    auto alloc = [&](size_t bytes) {
        char* p = ws + off;
        off += (bytes + 255) & ~(size_t)255;
        return p;
    };
    // zero-init region (small): gene counters + flag bitmask
    int*   gene_cnt      = (int*)alloc((size_t)NG * 4);
    unsigned int* flagw  = (unsigned int*)alloc((size_t)((n + 31) / 32) * 4);
    size_t zero_bytes    = off;
    // written-before-read region
    float*  t            = (float*)alloc((size_t)n * 4);       // zeroed by k_reduce
    float2* dx           = (float2*)alloc((size_t)n * 8);      // {dinv, dinv*x}
    int*    gene_src     = (int*)alloc((size_t)NG * GMAX * 4);
    size_t fixed         = off;

    int R = (n + HBINS - 1) / HBINS;                  // 6 for n=732160
    size_t per_copy = (size_t)R * HWORDS * 4;         // 384 KB per chunk
    int K = 80;                                       // mult of 8; 480 blocks ~ 512 slots
    if (fixed + (size_t)K * per_copy > ws_size) {
        size_t avail = (ws_size > fixed) ? (ws_size - fixed) : 0;
        int kfit = (int)(avail / per_copy);
        if (kfit >= 8) kfit &= ~7;                    // keep multiple of 8 for swizzle
        K = kfit < 1 ? 1 : (kfit < K ? kfit : K);
    }
    unsigned int* copies = (unsigned int*)alloc((size_t)K * per_copy);
    (void)n_in; (void)out_size;

    hipMemsetAsync(d_ws, 0, zero_bytes, stream);

    const int B = 256;
    k_hist<<<K * R, BHIST, 0, stream>>>(esrc, edst, copies, gene_cnt, gene_src,
                                        flagw, e, K, R);
    int Wtot = R * HWORDS;
    k_reduce<<<(Wtot + B - 1) / B, B, 0, stream>>>(copies, x, dx, t, flagw, n, K, Wtot);
    int e16b = (e >> 4) + 1;
    k_l1_scatter<<<(e16b + B - 1) / B, B, 0, stream>>>(esrc, edst, dx, flagw, t, e);
    int waves_blocks = (NG * 64 + B - 1) / B;
    k_gene_final<<<waves_blocks, B, 0, stream>>>(gene_cnt, gene_src, t, dx,
                                                 W1, b1, W2, b2,
                                                 fw1, fb1, fw2, fb2,
                                                 (float*)d_out, NG, G);
}

// Round 10
// 178.980 us; speedup vs baseline: 3.6408x; 1.1201x over previous
//
#include <hip/hip_runtime.h>

#define NODES 1430
#define GENE0 1421
#define NHEADS 9
#define HBINS 131072         // bins per block; 4-bit counts, 8 per u32
#define HWORDS (HBINS / 8)   // 16384 u32 words = 64 KB LDS (gfx9 per-WG max)
#define BHIST 1024           // 16 waves/block; 2 blocks/CU thread-cap
#define GMAX 64              // max bucketed in-edges per gene (Poisson(8) tail ~0)

__device__ __forceinline__ float frelu(float v) { return v > 0.f ? v : 0.f; }

// Pass 1: privatized LDS histogram (4-bit packed) of in-degree.
// 1-D grid of K*R blocks, XCD-swizzled (confirmed R8: FETCH 71->20 MB).
// Gene-detection distributed across ranges (no straggler tail).
__global__ __launch_bounds__(BHIST, 4)
void k_hist(const int* __restrict__ esrc, const int* __restrict__ edst,
            unsigned int* __restrict__ copies,      // [K][R*HWORDS]
            int* __restrict__ gene_cnt, int* __restrict__ gene_src,
            unsigned int* __restrict__ flagw,
            int e, int K, int R) {
    __shared__ unsigned int lds[HWORDS];
    int id = blockIdx.x;
    int k, r;
    if ((K & 7) == 0) {
        int xcd = id & 7;
        int slot = id >> 3;
        int cin = slot / R;
        k = xcd * (K >> 3) + cin;
        r = slot - cin * R;
    } else {
        k = id / R;
        r = id - k * R;
    }
    const int tid = threadIdx.x;
    {
        uint4* l4 = (uint4*)lds;
        for (int w = tid; w < HWORDS / 4; w += BHIST) l4[w] = make_uint4(0, 0, 0, 0);
    }
    __syncthreads();

    const unsigned int lo = (unsigned int)r * HBINS;
    const int e4 = e >> 2;
    const int Q = (e4 + K - 1) / K;
    const int beg = k * Q;
    const int end = min(beg + Q, e4);
    const int4* ed4 = (const int4*)edst;
    const int len = (end > beg) ? (end - beg) : 0;
    const int quarter = len >> 2;

    auto proc = [&](int4 d4) {
#pragma unroll
        for (int c = 0; c < 4; c++) {
            unsigned int d = (unsigned int)((&d4.x)[c]);
            unsigned int rel = d - lo;
            if (rel < HBINS)
                atomicAdd(&lds[rel >> 3], 1u << ((rel & 7u) * 4u));
        }
    };

    for (int i = tid; i < quarter; i += BHIST) {
        int j1 = beg + i;
        int j2 = j1 + quarter;
        int j3 = j2 + quarter;
        int j4 = j3 + quarter;
        int4 a = ed4[j1];
        int4 b = ed4[j2];
        int4 cc = ed4[j3];
        int4 dd = ed4[j4];
        proc(a); proc(b); proc(cc); proc(dd);
    }
    for (int i = (quarter << 2) + tid; i < len; i += BHIST) {
        proc(ed4[beg + i]);
    }

    // gene-scan: this block's sub-slice of the chunk (edges are L2-hot).
    {
        int sbeg = beg + (int)(((long long)len * r) / R);
        int send = beg + (int)(((long long)len * (r + 1)) / R);
        for (int j = sbeg + tid; j < send; j += BHIST) {
            int4 d4 = ed4[j];
#pragma unroll
            for (int c = 0; c < 4; c++) {
                unsigned int d = (unsigned int)((&d4.x)[c]);
                unsigned int graph = d / NODES;
                unsigned int pos = d - graph * NODES;
                if (pos >= GENE0) {
                    int s = esrc[4 * j + c];
                    atomicOr(&flagw[(unsigned)s >> 5], 1u << (s & 31));
                    int g = (int)(graph * NHEADS + (pos - GENE0));
                    int p = atomicAdd(gene_cnt + g, 1);
                    if (p < GMAX) gene_src[(g << 6) + p] = s;
                }
            }
        }
    }

    // tail edges (e % 4)
    if (k == 0) {
        for (int j = (e4 << 2) + tid; j < e; j += BHIST) {
            unsigned int d = (unsigned int)edst[j];
            unsigned int rel = d - lo;
            if (rel < HBINS)
                atomicAdd(&lds[rel >> 3], 1u << ((rel & 7u) * 4u));
            if (r == 0) {
                unsigned int graph = d / NODES;
                unsigned int pos = d - graph * NODES;
                if (pos >= GENE0) {
                    int s = esrc[j];
                    atomicOr(&flagw[(unsigned)s >> 5], 1u << (s & 31));
                    int g = (int)(graph * NHEADS + (pos - GENE0));
                    int p = atomicAdd(gene_cnt + g, 1);
                    if (p < GMAX) gene_src[(g << 6) + p] = s;
                }
            }
        }
    }
    __syncthreads();
    uint4* dst4 = (uint4*)(copies + ((size_t)k * R + r) * HWORDS);
    const uint4* l4 = (const uint4*)lds;
    for (int w = tid; w < HWORDS / 4; w += BHIST) dst4[w] = l4[w];
}

// Pass 2: sum K nibble-histograms (SWAR, 4-way unroll). Writes
// dx[i] = {dinv, dinv*x}, zeroes t, sets gene-node flag bits.
__global__ void k_reduce(const unsigned int* __restrict__ copies,
                         const float* __restrict__ x,
                         float2* __restrict__ dx, float* __restrict__ t,
                         unsigned int* __restrict__ flagw,
                         int n, int K, int Wtot) {
    int w = blockIdx.x * blockDim.x + threadIdx.x;
    if (w >= Wtot) return;
    const unsigned int M = 0x0F0F0F0Fu;
    unsigned int e0 = 0, o0 = 0, e1 = 0, o1 = 0, e2 = 0, o2 = 0, e3 = 0, o3 = 0;
    int k = 0;
    for (; k + 4 <= K; k += 4) {
        unsigned int u0 = copies[(size_t)(k + 0) * Wtot + w];
        unsigned int u1 = copies[(size_t)(k + 1) * Wtot + w];
        unsigned int u2 = copies[(size_t)(k + 2) * Wtot + w];
        unsigned int u3 = copies[(size_t)(k + 3) * Wtot + w];
        e0 += u0 & M; o0 += (u0 >> 4) & M;
        e1 += u1 & M; o1 += (u1 >> 4) & M;
        e2 += u2 & M; o2 += (u2 >> 4) & M;
        e3 += u3 & M; o3 += (u3 >> 4) & M;
    }
    for (; k < K; k++) {
        unsigned int u = copies[(size_t)k * Wtot + w];
        e0 += u & M; o0 += (u >> 4) & M;
    }
    unsigned int evn = e0 + e1 + e2 + e3;
    unsigned int odd = o0 + o1 + o2 + o3;
    int i0 = w << 3;
    float v[8];
#pragma unroll
    for (int b = 0; b < 4; b++) {
        v[2 * b]     = (float)((evn >> (8 * b)) & 0xFFu);
        v[2 * b + 1] = (float)((odd >> (8 * b)) & 0xFFu);
    }
#pragma unroll
    for (int b = 0; b < 8; b++) v[b] = rsqrtf(v[b] + 1.f);
    float4 z4 = {0.f, 0.f, 0.f, 0.f};
    if (i0 + 7 < n) {
        float4 xa = *(const float4*)(x + i0);
        float4 xb = *(const float4*)(x + i0 + 4);
        float4 p0 = {v[0], v[0] * xa.x, v[1], v[1] * xa.y};
        float4 p1 = {v[2], v[2] * xa.z, v[3], v[3] * xa.w};
        float4 p2 = {v[4], v[4] * xb.x, v[5], v[5] * xb.y};
        float4 p3 = {v[6], v[6] * xb.z, v[7], v[7] * xb.w};
        float4* dst = (float4*)(dx + i0);
        dst[0] = p0; dst[1] = p1; dst[2] = p2; dst[3] = p3;
        *(float4*)(t + i0) = z4;
        *(float4*)(t + i0 + 4) = z4;
    } else {
        for (int b = 0; b < 8; b++)
            if (i0 + b < n) {
                float xv = x[i0 + b];
                dx[i0 + b] = make_float2(v[b], v[b] * xv);
                t[i0 + b] = 0.f;
            }
    }
#pragma unroll
    for (int b = 0; b < 8; b++) {
        int i = i0 + b;
        if (i < n) {
            unsigned int graph = (unsigned int)i / NODES;
            unsigned int pos = (unsigned int)i - graph * NODES;
            if (pos >= GENE0) atomicOr(&flagw[(unsigned)i >> 5], 1u << (i & 31));
        }
    }
}

// Pass 3: layer-1 scatter into flagged dst only (~5.6% of edges).
__global__ void k_l1_scatter(const int* __restrict__ esrc, const int* __restrict__ edst,
                             const float2* __restrict__ dx,
                             const unsigned int* __restrict__ flagw,
                             float* __restrict__ t, int e) {
    int q = blockIdx.x * blockDim.x + threadIdx.x;
    int e16 = e >> 4;
    if (q < e16) {
        const int4* ed4 = (const int4*)edst;
        const int4* es4 = (const int4*)esrc;
        int4 d0 = ed4[4 * q + 0];
        int4 d1 = ed4[4 * q + 1];
        int4 d2 = ed4[4 * q + 2];
        int4 d3 = ed4[4 * q + 3];
        int4 s0 = es4[4 * q + 0];
        int4 s1 = es4[4 * q + 1];
        int4 s2 = es4[4 * q + 2];
        int4 s3 = es4[4 * q + 3];
        auto scat = [&](int4 dd, int4 ss) {
#pragma unroll
            for (int c = 0; c < 4; c++) {
                int d = (&dd.x)[c];
                if ((flagw[(unsigned)d >> 5] >> (d & 31)) & 1u) {
                    int s = (&ss.x)[c];
                    atomicAdd(t + d, dx[s].y);
                }
            }
        };
        scat(d0, s0); scat(d1, s1); scat(d2, s2); scat(d3, s3);
    } else if (q == e16) {
        for (int j = e16 << 4; j < e; j++) {
            int d = edst[j];
            if (!((flagw[(unsigned)d >> 5] >> (d & 31)) & 1u)) continue;
            int s = esrc[j];
            atomicAdd(t + d, dx[s].y);
        }
    }
}

// Pass 4 (channel-parallel): one WAVE per gene. Lane = (channel c 0-15,
// edge-slot 0-3). Each lane accumulates its channel over its edge slots
// (gene_src terminated by -1 sentinel; no gene_cnt read). Reduce = 2 shfl.
// Finalize + h2 vectorized over the 16 channel-lanes; head MLP via 16
// broadcast shfl + 3-step 8-lane reduce.
__global__ void k_gene_final(const int* __restrict__ gene_src,
                             const float* __restrict__ t, const float2* __restrict__ dx,
                             const float* __restrict__ W1, const float* __restrict__ b1,
                             const float* __restrict__ W2, const float* __restrict__ b2,
                             const float* __restrict__ fw1, const float* __restrict__ fb1,
                             const float* __restrict__ fw2, const float* __restrict__ fb2,
                             float* __restrict__ out, int NG, int G) {
    int wid = (blockIdx.x * blockDim.x + threadIdx.x) >> 6;
    int lane = threadIdx.x & 63;
    if (wid >= NG) return;
    int g = wid;
    int graph = g / NHEADS;
    int head = g - graph * NHEADS;
    int node = graph * NODES + GENE0 + head;
    const int c = lane & 15;
    const int slot = lane >> 4;

    // hoist weights for this channel into registers
    float w1r[16], b1r[16], w2c[16];
#pragma unroll
    for (int kk = 0; kk < 16; kk++) {
        w1r[kk] = W1[kk];
        b1r[kk] = b1[kk];
        w2c[kk] = W2[kk * 16 + c];
    }
    // node self-term loads issued early (independent of edge loop)
    float2 dn2 = dx[node];
    float tn = t[node];

    float acc = 0.f;
    const int base = g << 6;
    for (int i = slot; i < GMAX; i += 4) {
        int s = gene_src[base + i];
        if (s < 0) break;                 // sentinel: bucket exhausted
        float2 ds2 = dx[s];
        float ts = t[s];
        float us = ds2.x * ts + ds2.x * ds2.y;
        float m = 0.f;
#pragma unroll
        for (int kk = 0; kk < 16; kk++)
            m += frelu(us * w1r[kk] + b1r[kk]) * w2c[kk];
        acc += ds2.x * m;
    }
    // sum the 4 edge-slots per channel (every lane ends with its channel total)
    acc += __shfl_xor(acc, 16, 64);
    acc += __shfl_xor(acc, 32, 64);

    // finalize channel c
    float dn = dn2.x;
    float un = dn * tn + dn * dn2.y;
    float h2 = 0.f;
#pragma unroll
    for (int kk = 0; kk < 16; kk++)
        h2 += frelu(un * w1r[kk] + b1r[kk]) * w2c[kk];
    float h = frelu(dn * acc + dn * dn * h2 + b2[c]);

    // broadcast all 16 channel values to every lane
    float hv[16];
#pragma unroll
    for (int c2 = 0; c2 < 16; c2++) hv[c2] = __shfl(h, c2, 64);

    // head MLP: lane kk (mod 8) computes hidden unit kk
    int kk = lane & 7;
    float z = fb1[head * 8 + kk];
#pragma unroll
    for (int c2 = 0; c2 < 16; c2++) z += hv[c2] * fw1[head * 128 + c2 * 8 + kk];
    float term = frelu(z) * fw2[head * 8 + kk];
    term += __shfl_xor(term, 1, 64);
    term += __shfl_xor(term, 2, 64);
    term += __shfl_xor(term, 4, 64);
    if (lane == 0) out[head * G + graph] = fb2[head] + term;
}

extern "C" void kernel_launch(void* const* d_in, const int* in_sizes, int n_in,
                              void* d_out, int out_size, void* d_ws, size_t ws_size,
                              hipStream_t stream) {
    const float* x   = (const float*)d_in[0];
    const int*   ei  = (const int*)d_in[1];
    const float* W1  = (const float*)d_in[3];
    const float* b1  = (const float*)d_in[4];
    const float* W2  = (const float*)d_in[5];
    const float* b2  = (const float*)d_in[6];
    const float* fw1 = (const float*)d_in[7];
    const float* fb1 = (const float*)d_in[8];
    const float* fw2 = (const float*)d_in[9];
    const float* fb2 = (const float*)d_in[10];

    int n = in_sizes[0];
    int e = in_sizes[1] / 2;
    int G = in_sizes[2] / NHEADS;
    int NG = G * NHEADS;
    const int* esrc = ei;
    const int* edst = ei + e;

    char* ws = (char*)d_ws;
    size_t off = 0;
    auto alloc = [&](size_t bytes) {
        char* p = ws + off;
        off += (bytes + 255) & ~(size_t)255;
        return p;
    };
    // zero-init region: gene counters + flag bitmask
    int*   gene_cnt      = (int*)alloc((size_t)NG * 4);
    unsigned int* flagw  = (unsigned int*)alloc((size_t)((n + 31) / 32) * 4);
    size_t zero_bytes    = off;
    // 0xFF-init region: gene_src sentinel = -1
    int*    gene_src     = (int*)alloc((size_t)NG * GMAX * 4);
    size_t ff_bytes      = (size_t)NG * GMAX * 4;
    // written-before-read region
    float*  t            = (float*)alloc((size_t)n * 4);       // zeroed by k_reduce
    float2* dx           = (float2*)alloc((size_t)n * 8);      // {dinv, dinv*x}
    size_t fixed         = off;

    int R = (n + HBINS - 1) / HBINS;                  // 6 for n=732160
    size_t per_copy = (size_t)R * HWORDS * 4;         // 384 KB per chunk
    int K = 80;                                       // mult of 8; 480 blocks ~ 512 slots
    if (fixed + (size_t)K * per_copy > ws_size) {
        size_t avail = (ws_size > fixed) ? (ws_size - fixed) : 0;
        int kfit = (int)(avail / per_copy);
        if (kfit >= 8) kfit &= ~7;
        K = kfit < 1 ? 1 : (kfit < K ? kfit : K);
    }
    unsigned int* copies = (unsigned int*)alloc((size_t)K * per_copy);
    (void)n_in; (void)out_size;

    hipMemsetAsync(d_ws, 0, zero_bytes, stream);
    hipMemsetAsync(gene_src, 0xFF, ff_bytes, stream);

    const int B = 256;
    k_hist<<<K * R, BHIST, 0, stream>>>(esrc, edst, copies, gene_cnt, gene_src,
                                        flagw, e, K, R);
    int Wtot = R * HWORDS;
    k_reduce<<<(Wtot + B - 1) / B, B, 0, stream>>>(copies, x, dx, t, flagw, n, K, Wtot);
    int e16b = (e >> 4) + 1;
    k_l1_scatter<<<(e16b + B - 1) / B, B, 0, stream>>>(esrc, edst, dx, flagw, t, e);
    int waves_blocks = (NG * 64 + B - 1) / B;
    k_gene_final<<<waves_blocks, B, 0, stream>>>(gene_src, t, dx,
                                                 W1, b1, W2, b2,
                                                 fw1, fb1, fw2, fb2,
                                                 (float*)d_out, NG, G);
}

// Round 11
// 177.468 us; speedup vs baseline: 3.6719x; 1.0085x over previous
//
#include <hip/hip_runtime.h>

#define NODES 1430
#define GENE0 1421
#define NHEADS 9
#define HBINS 131072         // bins per block; 4-bit counts, 8 per u32
#define HWORDS (HBINS / 8)   // 16384 u32 words = 64 KB LDS (gfx9 per-WG max)
#define BHIST 1024           // 16 waves/block; 2 blocks/CU thread-cap
#define GMAX 64              // max bucketed in-edges per gene (Poisson(8) tail ~0)
#define QCAP 2048            // hit-queue capacity (expected ~230/block, 54 sigma margin)

__device__ __forceinline__ float frelu(float v) { return v > 0.f ? v : 0.f; }

// Pass 1: privatized LDS histogram (4-bit packed) of in-degree.
// 1-D grid of K*R blocks, XCD-swizzled (confirmed R8: FETCH 71->20 MB).
// Gene-detection distributed across ranges (no straggler tail).
__global__ __launch_bounds__(BHIST, 4)
void k_hist(const int* __restrict__ esrc, const int* __restrict__ edst,
            unsigned int* __restrict__ copies,      // [K][R*HWORDS]
            int* __restrict__ gene_cnt, int* __restrict__ gene_src,
            unsigned int* __restrict__ flagw,
            int e, int K, int R) {
    __shared__ unsigned int lds[HWORDS];
    int id = blockIdx.x;
    int k, r;
    if ((K & 7) == 0) {
        int xcd = id & 7;
        int slot = id >> 3;
        int cin = slot / R;
        k = xcd * (K >> 3) + cin;
        r = slot - cin * R;
    } else {
        k = id / R;
        r = id - k * R;
    }
    const int tid = threadIdx.x;
    {
        uint4* l4 = (uint4*)lds;
        for (int w = tid; w < HWORDS / 4; w += BHIST) l4[w] = make_uint4(0, 0, 0, 0);
    }
    __syncthreads();

    const unsigned int lo = (unsigned int)r * HBINS;
    const int e4 = e >> 2;
    const int Q = (e4 + K - 1) / K;
    const int beg = k * Q;
    const int end = min(beg + Q, e4);
    const int4* ed4 = (const int4*)edst;
    const int len = (end > beg) ? (end - beg) : 0;
    const int quarter = len >> 2;

    auto proc = [&](int4 d4) {
#pragma unroll
        for (int c = 0; c < 4; c++) {
            unsigned int d = (unsigned int)((&d4.x)[c]);
            unsigned int rel = d - lo;
            if (rel < HBINS)
                atomicAdd(&lds[rel >> 3], 1u << ((rel & 7u) * 4u));
        }
    };

    for (int i = tid; i < quarter; i += BHIST) {
        int j1 = beg + i;
        int j2 = j1 + quarter;
        int j3 = j2 + quarter;
        int j4 = j3 + quarter;
        int4 a = ed4[j1];
        int4 b = ed4[j2];
        int4 cc = ed4[j3];
        int4 dd = ed4[j4];
        proc(a); proc(b); proc(cc); proc(dd);
    }
    for (int i = (quarter << 2) + tid; i < len; i += BHIST) {
        proc(ed4[beg + i]);
    }

    // gene-scan: this block's sub-slice of the chunk (edges are L2-hot).
    {
        int sbeg = beg + (int)(((long long)len * r) / R);
        int send = beg + (int)(((long long)len * (r + 1)) / R);
        for (int j = sbeg + tid; j < send; j += BHIST) {
            int4 d4 = ed4[j];
#pragma unroll
            for (int c = 0; c < 4; c++) {
                unsigned int d = (unsigned int)((&d4.x)[c]);
                unsigned int graph = d / NODES;
                unsigned int pos = d - graph * NODES;
                if (pos >= GENE0) {
                    int s = esrc[4 * j + c];
                    atomicOr(&flagw[(unsigned)s >> 5], 1u << (s & 31));
                    int g = (int)(graph * NHEADS + (pos - GENE0));
                    int p = atomicAdd(gene_cnt + g, 1);
                    if (p < GMAX) gene_src[(g << 6) + p] = s;
                }
            }
        }
    }

    // tail edges (e % 4)
    if (k == 0) {
        for (int j = (e4 << 2) + tid; j < e; j += BHIST) {
            unsigned int d = (unsigned int)edst[j];
            unsigned int rel = d - lo;
            if (rel < HBINS)
                atomicAdd(&lds[rel >> 3], 1u << ((rel & 7u) * 4u));
            if (r == 0) {
                unsigned int graph = d / NODES;
                unsigned int pos = d - graph * NODES;
                if (pos >= GENE0) {
                    int s = esrc[j];
                    atomicOr(&flagw[(unsigned)s >> 5], 1u << (s & 31));
                    int g = (int)(graph * NHEADS + (pos - GENE0));
                    int p = atomicAdd(gene_cnt + g, 1);
                    if (p < GMAX) gene_src[(g << 6) + p] = s;
                }
            }
        }
    }
    __syncthreads();
    uint4* dst4 = (uint4*)(copies + ((size_t)k * R + r) * HWORDS);
    const uint4* l4 = (const uint4*)lds;
    for (int w = tid; w < HWORDS / 4; w += BHIST) dst4[w] = l4[w];
}

// Pass 2: sum K nibble-histograms (SWAR, 4-way unroll). Writes
// dx[i] = {dinv, dinv*x}, zeroes t, sets gene-node flag bits.
__global__ void k_reduce(const unsigned int* __restrict__ copies,
                         const float* __restrict__ x,
                         float2* __restrict__ dx, float* __restrict__ t,
                         unsigned int* __restrict__ flagw,
                         int n, int K, int Wtot) {
    int w = blockIdx.x * blockDim.x + threadIdx.x;
    if (w >= Wtot) return;
    const unsigned int M = 0x0F0F0F0Fu;
    unsigned int e0 = 0, o0 = 0, e1 = 0, o1 = 0, e2 = 0, o2 = 0, e3 = 0, o3 = 0;
    int k = 0;
    for (; k + 4 <= K; k += 4) {
        unsigned int u0 = copies[(size_t)(k + 0) * Wtot + w];
        unsigned int u1 = copies[(size_t)(k + 1) * Wtot + w];
        unsigned int u2 = copies[(size_t)(k + 2) * Wtot + w];
        unsigned int u3 = copies[(size_t)(k + 3) * Wtot + w];
        e0 += u0 & M; o0 += (u0 >> 4) & M;
        e1 += u1 & M; o1 += (u1 >> 4) & M;
        e2 += u2 & M; o2 += (u2 >> 4) & M;
        e3 += u3 & M; o3 += (u3 >> 4) & M;
    }
    for (; k < K; k++) {
        unsigned int u = copies[(size_t)k * Wtot + w];
        e0 += u & M; o0 += (u >> 4) & M;
    }
    unsigned int evn = e0 + e1 + e2 + e3;
    unsigned int odd = o0 + o1 + o2 + o3;
    int i0 = w << 3;
    float v[8];
#pragma unroll
    for (int b = 0; b < 4; b++) {
        v[2 * b]     = (float)((evn >> (8 * b)) & 0xFFu);
        v[2 * b + 1] = (float)((odd >> (8 * b)) & 0xFFu);
    }
#pragma unroll
    for (int b = 0; b < 8; b++) v[b] = rsqrtf(v[b] + 1.f);
    float4 z4 = {0.f, 0.f, 0.f, 0.f};
    if (i0 + 7 < n) {
        float4 xa = *(const float4*)(x + i0);
        float4 xb = *(const float4*)(x + i0 + 4);
        float4 p0 = {v[0], v[0] * xa.x, v[1], v[1] * xa.y};
        float4 p1 = {v[2], v[2] * xa.z, v[3], v[3] * xa.w};
        float4 p2 = {v[4], v[4] * xb.x, v[5], v[5] * xb.y};
        float4 p3 = {v[6], v[6] * xb.z, v[7], v[7] * xb.w};
        float4* dst = (float4*)(dx + i0);
        dst[0] = p0; dst[1] = p1; dst[2] = p2; dst[3] = p3;
        *(float4*)(t + i0) = z4;
        *(float4*)(t + i0 + 4) = z4;
    } else {
        for (int b = 0; b < 8; b++)
            if (i0 + b < n) {
                float xv = x[i0 + b];
                dx[i0 + b] = make_float2(v[b], v[b] * xv);
                t[i0 + b] = 0.f;
            }
    }
#pragma unroll
    for (int b = 0; b < 8; b++) {
        int i = i0 + b;
        if (i < n) {
            unsigned int graph = (unsigned int)i / NODES;
            unsigned int pos = (unsigned int)i - graph * NODES;
            if (pos >= GENE0) atomicOr(&flagw[(unsigned)i >> 5], 1u << (i & 31));
        }
    }
}

// Pass 3: layer-1 scatter into flagged dst only (~5.6% of edges).
// Scan phase pushes hit (s,d) pairs to an LDS queue (no dependent global
// work in the scan); drain phase processes all hits in parallel.
__global__ __launch_bounds__(256, 8)
void k_l1_scatter(const int* __restrict__ esrc, const int* __restrict__ edst,
                  const float2* __restrict__ dx,
                  const unsigned int* __restrict__ flagw,
                  float* __restrict__ t, int e) {
    __shared__ int2 q[QCAP];
    __shared__ int qn;
    const int tid = threadIdx.x;
    if (tid == 0) qn = 0;
    __syncthreads();

    const int4* ed4 = (const int4*)edst;
    const int4* es4 = (const int4*)esrc;
    const int e4 = e >> 2;
    const int g0 = blockIdx.x * 1024;     // int4-group base; block covers 4096 edges
#pragma unroll
    for (int u = 0; u < 4; u++) {
        int gi = g0 + u * 256 + tid;
        if (gi < e4) {
            int4 dd = ed4[gi];
            int4 ss = es4[gi];
#pragma unroll
            for (int c = 0; c < 4; c++) {
                int d = (&dd.x)[c];
                if ((flagw[(unsigned)d >> 5] >> (d & 31)) & 1u) {
                    int p = atomicAdd(&qn, 1);
                    if (p < QCAP) q[p] = make_int2((&ss.x)[c], d);
                    else atomicAdd(t + d, dx[(&ss.x)[c]].y);   // overflow fallback
                }
            }
        }
    }
    // tail edges (e % 4) — block 0 handles inline
    if (blockIdx.x == 0) {
        for (int j = (e4 << 2) + tid; j < e; j += 256) {
            int d = edst[j];
            if ((flagw[(unsigned)d >> 5] >> (d & 31)) & 1u) {
                int s = esrc[j];
                atomicAdd(t + d, dx[s].y);
            }
        }
    }
    __syncthreads();
    int m = min(qn, QCAP);
    for (int i = tid; i < m; i += 256) {
        int2 sd = q[i];
        atomicAdd(t + sd.y, dx[sd.x].y);
    }
}

// Pass 4 (channel-parallel): one WAVE per gene. Lane = (channel c 0-15,
// edge-slot 0-3). Each lane accumulates its channel over its edge slots.
// Reduce = 2 shfl; finalize + h2 vectorized over the 16 channel-lanes;
// head MLP via 16 broadcast shfl + 3-step 8-lane reduce.
__global__ void k_gene_final(const int* __restrict__ gene_cnt, const int* __restrict__ gene_src,
                             const float* __restrict__ t, const float2* __restrict__ dx,
                             const float* __restrict__ W1, const float* __restrict__ b1,
                             const float* __restrict__ W2, const float* __restrict__ b2,
                             const float* __restrict__ fw1, const float* __restrict__ fb1,
                             const float* __restrict__ fw2, const float* __restrict__ fb2,
                             float* __restrict__ out, int NG, int G) {
    int wid = (blockIdx.x * blockDim.x + threadIdx.x) >> 6;
    int lane = threadIdx.x & 63;
    if (wid >= NG) return;
    int g = wid;
    int graph = g / NHEADS;
    int head = g - graph * NHEADS;
    int node = graph * NODES + GENE0 + head;
    const int c = lane & 15;
    const int slot = lane >> 4;

    int cnt = min(gene_cnt[g], GMAX);     // early scalar load

    float w1r[16], b1r[16], w2c[16];
#pragma unroll
    for (int kk = 0; kk < 16; kk++) {
        w1r[kk] = W1[kk];
        b1r[kk] = b1[kk];
        w2c[kk] = W2[kk * 16 + c];
    }
    float2 dn2 = dx[node];
    float tn = t[node];

    float acc = 0.f;
    const int base = g << 6;
    for (int i = slot; i < cnt; i += 4) {
        int s = gene_src[base + i];
        float2 ds2 = dx[s];
        float ts = t[s];
        float us = ds2.x * ts + ds2.x * ds2.y;
        float m = 0.f;
#pragma unroll
        for (int kk = 0; kk < 16; kk++)
            m += frelu(us * w1r[kk] + b1r[kk]) * w2c[kk];
        acc += ds2.x * m;
    }
    acc += __shfl_xor(acc, 16, 64);
    acc += __shfl_xor(acc, 32, 64);

    float dn = dn2.x;
    float un = dn * tn + dn * dn2.y;
    float h2 = 0.f;
#pragma unroll
    for (int kk = 0; kk < 16; kk++)
        h2 += frelu(un * w1r[kk] + b1r[kk]) * w2c[kk];
    float h = frelu(dn * acc + dn * dn * h2 + b2[c]);

    float hv[16];
#pragma unroll
    for (int c2 = 0; c2 < 16; c2++) hv[c2] = __shfl(h, c2, 64);

    int kk = lane & 7;
    float z = fb1[head * 8 + kk];
#pragma unroll
    for (int c2 = 0; c2 < 16; c2++) z += hv[c2] * fw1[head * 128 + c2 * 8 + kk];
    float term = frelu(z) * fw2[head * 8 + kk];
    term += __shfl_xor(term, 1, 64);
    term += __shfl_xor(term, 2, 64);
    term += __shfl_xor(term, 4, 64);
    if (lane == 0) out[head * G + graph] = fb2[head] + term;
}

extern "C" void kernel_launch(void* const* d_in, const int* in_sizes, int n_in,
                              void* d_out, int out_size, void* d_ws, size_t ws_size,
                              hipStream_t stream) {
    const float* x   = (const float*)d_in[0];
    const int*   ei  = (const int*)d_in[1];
    const float* W1  = (const float*)d_in[3];
    const float* b1  = (const float*)d_in[4];
    const float* W2  = (const float*)d_in[5];
    const float* b2  = (const float*)d_in[6];
    const float* fw1 = (const float*)d_in[7];
    const float* fb1 = (const float*)d_in[8];
    const float* fw2 = (const float*)d_in[9];
    const float* fb2 = (const float*)d_in[10];

    int n = in_sizes[0];
    int e = in_sizes[1] / 2;
    int G = in_sizes[2] / NHEADS;
    int NG = G * NHEADS;
    const int* esrc = ei;
    const int* edst = ei + e;

    char* ws = (char*)d_ws;
    size_t off = 0;
    auto alloc = [&](size_t bytes) {
        char* p = ws + off;
        off += (bytes + 255) & ~(size_t)255;
        return p;
    };
    // zero-init region: gene counters + flag bitmask
    int*   gene_cnt      = (int*)alloc((size_t)NG * 4);
    unsigned int* flagw  = (unsigned int*)alloc((size_t)((n + 31) / 32) * 4);
    size_t zero_bytes    = off;
    // written-before-read region
    int*    gene_src     = (int*)alloc((size_t)NG * GMAX * 4);
    float*  t            = (float*)alloc((size_t)n * 4);       // zeroed by k_reduce
    float2* dx           = (float2*)alloc((size_t)n * 8);      // {dinv, dinv*x}
    size_t fixed         = off;

    int R = (n + HBINS - 1) / HBINS;                  // 6 for n=732160
    size_t per_copy = (size_t)R * HWORDS * 4;         // 384 KB per chunk
    int K = 80;                                       // mult of 8; 480 blocks ~ 512 slots
    if (fixed + (size_t)K * per_copy > ws_size) {
        size_t avail = (ws_size > fixed) ? (ws_size - fixed) : 0;
        int kfit = (int)(avail / per_copy);
        if (kfit >= 8) kfit &= ~7;
        K = kfit < 1 ? 1 : (kfit < K ? kfit : K);
    }
    unsigned int* copies = (unsigned int*)alloc((size_t)K * per_copy);
    (void)n_in; (void)out_size;

    hipMemsetAsync(d_ws, 0, zero_bytes, stream);

    const int B = 256;
    k_hist<<<K * R, BHIST, 0, stream>>>(esrc, edst, copies, gene_cnt, gene_src,
                                        flagw, e, K, R);
    int Wtot = R * HWORDS;
    k_reduce<<<(Wtot + B - 1) / B, B, 0, stream>>>(copies, x, dx, t, flagw, n, K, Wtot);
    int nblk = ((e >> 2) + 1023) / 1024;              // 4096 edges per block
    k_l1_scatter<<<nblk, 256, 0, stream>>>(esrc, edst, dx, flagw, t, e);
    int waves_blocks = (NG * 64 + B - 1) / B;
    k_gene_final<<<waves_blocks, B, 0, stream>>>(gene_cnt, gene_src, t, dx,
                                                 W1, b1, W2, b2,
                                                 fw1, fb1, fw2, fb2,
                                                 (float*)d_out, NG, G);
}

// Round 12
// 172.367 us; speedup vs baseline: 3.7805x; 1.0296x over previous
//
#include <hip/hip_runtime.h>

#define NODES 1430
#define GENE0 1421
#define NHEADS 9
#define HBINS 131072         // bins per block; 4-bit counts, 8 per u32
#define HWORDS (HBINS / 8)   // 16384 u32 words = 64 KB LDS (gfx9 per-WG max)
#define BHIST 1024           // 16 waves/block; 2 blocks/CU thread-cap
#define GMAX 64              // max bucketed in-edges per gene (Poisson(8) tail ~0)
#define QCAP 1024            // hit-queue capacity (expected ~115/block at 2048 edges)

__device__ __forceinline__ float frelu(float v) { return v > 0.f ? v : 0.f; }

// Pass 1: privatized LDS histogram (4-bit packed) of in-degree.
// 1-D grid of K*R blocks, XCD-swizzled (confirmed R8: FETCH 71->20 MB).
// Gene-detection distributed across ranges (no straggler tail).
__global__ __launch_bounds__(BHIST, 4)
void k_hist(const int* __restrict__ esrc, const int* __restrict__ edst,
            unsigned int* __restrict__ copies,      // [K][R*HWORDS]
            int* __restrict__ gene_cnt, int* __restrict__ gene_src,
            unsigned int* __restrict__ flagw,
            int e, int K, int R) {
    __shared__ unsigned int lds[HWORDS];
    int id = blockIdx.x;
    int k, r;
    if ((K & 7) == 0) {
        int xcd = id & 7;
        int slot = id >> 3;
        int cin = slot / R;
        k = xcd * (K >> 3) + cin;
        r = slot - cin * R;
    } else {
        k = id / R;
        r = id - k * R;
    }
    const int tid = threadIdx.x;
    {
        uint4* l4 = (uint4*)lds;
        for (int w = tid; w < HWORDS / 4; w += BHIST) l4[w] = make_uint4(0, 0, 0, 0);
    }
    __syncthreads();

    const unsigned int lo = (unsigned int)r * HBINS;
    const int e4 = e >> 2;
    const int Q = (e4 + K - 1) / K;
    const int beg = k * Q;
    const int end = min(beg + Q, e4);
    const int4* ed4 = (const int4*)edst;
    const int len = (end > beg) ? (end - beg) : 0;
    const int quarter = len >> 2;

    auto proc = [&](int4 d4) {
#pragma unroll
        for (int c = 0; c < 4; c++) {
            unsigned int d = (unsigned int)((&d4.x)[c]);
            unsigned int rel = d - lo;
            if (rel < HBINS)
                atomicAdd(&lds[rel >> 3], 1u << ((rel & 7u) * 4u));
        }
    };

    for (int i = tid; i < quarter; i += BHIST) {
        int j1 = beg + i;
        int j2 = j1 + quarter;
        int j3 = j2 + quarter;
        int j4 = j3 + quarter;
        int4 a = ed4[j1];
        int4 b = ed4[j2];
        int4 cc = ed4[j3];
        int4 dd = ed4[j4];
        proc(a); proc(b); proc(cc); proc(dd);
    }
    for (int i = (quarter << 2) + tid; i < len; i += BHIST) {
        proc(ed4[beg + i]);
    }

    // gene-scan: this block's sub-slice of the chunk (edges are L2-hot).
    {
        int sbeg = beg + (int)(((long long)len * r) / R);
        int send = beg + (int)(((long long)len * (r + 1)) / R);
        for (int j = sbeg + tid; j < send; j += BHIST) {
            int4 d4 = ed4[j];
#pragma unroll
            for (int c = 0; c < 4; c++) {
                unsigned int d = (unsigned int)((&d4.x)[c]);
                unsigned int graph = d / NODES;
                unsigned int pos = d - graph * NODES;
                if (pos >= GENE0) {
                    int s = esrc[4 * j + c];
                    atomicOr(&flagw[(unsigned)s >> 5], 1u << (s & 31));
                    int g = (int)(graph * NHEADS + (pos - GENE0));
                    int p = atomicAdd(gene_cnt + g, 1);
                    if (p < GMAX) gene_src[(g << 6) + p] = s;
                }
            }
        }
    }

    // tail edges (e % 4)
    if (k == 0) {
        for (int j = (e4 << 2) + tid; j < e; j += BHIST) {
            unsigned int d = (unsigned int)edst[j];
            unsigned int rel = d - lo;
            if (rel < HBINS)
                atomicAdd(&lds[rel >> 3], 1u << ((rel & 7u) * 4u));
            if (r == 0) {
                unsigned int graph = d / NODES;
                unsigned int pos = d - graph * NODES;
                if (pos >= GENE0) {
                    int s = esrc[j];
                    atomicOr(&flagw[(unsigned)s >> 5], 1u << (s & 31));
                    int g = (int)(graph * NHEADS + (pos - GENE0));
                    int p = atomicAdd(gene_cnt + g, 1);
                    if (p < GMAX) gene_src[(g << 6) + p] = s;
                }
            }
        }
    }
    __syncthreads();
    uint4* dst4 = (uint4*)(copies + ((size_t)k * R + r) * HWORDS);
    const uint4* l4 = (const uint4*)lds;
    for (int w = tid; w < HWORDS / 4; w += BHIST) dst4[w] = l4[w];
}

// Pass 2: sum K nibble-histograms (SWAR, 8 independent streams). Writes
// dx[i] = {dinv, dinv*x}, zeroes t, sets gene-node flag bits.
// Byte-lane safety: every partial/final byte sum <= true degree <= 255.
__global__ void k_reduce(const unsigned int* __restrict__ copies,
                         const float* __restrict__ x,
                         float2* __restrict__ dx, float* __restrict__ t,
                         unsigned int* __restrict__ flagw,
                         int n, int K, int Wtot) {
    int w = blockIdx.x * blockDim.x + threadIdx.x;
    if (w >= Wtot) return;
    const unsigned int M = 0x0F0F0F0Fu;
    unsigned int ev[8] = {0, 0, 0, 0, 0, 0, 0, 0};
    unsigned int od[8] = {0, 0, 0, 0, 0, 0, 0, 0};
    int k = 0;
    for (; k + 8 <= K; k += 8) {
#pragma unroll
        for (int s = 0; s < 8; s++) {
            unsigned int u = copies[(size_t)(k + s) * Wtot + w];
            ev[s] += u & M; od[s] += (u >> 4) & M;
        }
    }
    for (; k < K; k++) {
        unsigned int u = copies[(size_t)k * Wtot + w];
        ev[0] += u & M; od[0] += (u >> 4) & M;
    }
    unsigned int evn = ((ev[0] + ev[1]) + (ev[2] + ev[3])) + ((ev[4] + ev[5]) + (ev[6] + ev[7]));
    unsigned int odd = ((od[0] + od[1]) + (od[2] + od[3])) + ((od[4] + od[5]) + (od[6] + od[7]));
    int i0 = w << 3;
    float v[8];
#pragma unroll
    for (int b = 0; b < 4; b++) {
        v[2 * b]     = (float)((evn >> (8 * b)) & 0xFFu);
        v[2 * b + 1] = (float)((odd >> (8 * b)) & 0xFFu);
    }
#pragma unroll
    for (int b = 0; b < 8; b++) v[b] = rsqrtf(v[b] + 1.f);
    float4 z4 = {0.f, 0.f, 0.f, 0.f};
    if (i0 + 7 < n) {
        float4 xa = *(const float4*)(x + i0);
        float4 xb = *(const float4*)(x + i0 + 4);
        float4 p0 = {v[0], v[0] * xa.x, v[1], v[1] * xa.y};
        float4 p1 = {v[2], v[2] * xa.z, v[3], v[3] * xa.w};
        float4 p2 = {v[4], v[4] * xb.x, v[5], v[5] * xb.y};
        float4 p3 = {v[6], v[6] * xb.z, v[7], v[7] * xb.w};
        float4* dst = (float4*)(dx + i0);
        dst[0] = p0; dst[1] = p1; dst[2] = p2; dst[3] = p3;
        *(float4*)(t + i0) = z4;
        *(float4*)(t + i0 + 4) = z4;
    } else {
        for (int b = 0; b < 8; b++)
            if (i0 + b < n) {
                float xv = x[i0 + b];
                dx[i0 + b] = make_float2(v[b], v[b] * xv);
                t[i0 + b] = 0.f;
            }
    }
#pragma unroll
    for (int b = 0; b < 8; b++) {
        int i = i0 + b;
        if (i < n) {
            unsigned int graph = (unsigned int)i / NODES;
            unsigned int pos = (unsigned int)i - graph * NODES;
            if (pos >= GENE0) atomicOr(&flagw[(unsigned)i >> 5], 1u << (i & 31));
        }
    }
}

// Pass 3: layer-1 scatter into flagged dst only (~5.6% of edges).
// 2048 edges/block -> 2860 blocks (grid no longer occupancy-limiting).
// Scan pushes hit (s,d) pairs to an LDS queue; drain processes in parallel.
__global__ __launch_bounds__(256, 8)
void k_l1_scatter(const int* __restrict__ esrc, const int* __restrict__ edst,
                  const float2* __restrict__ dx,
                  const unsigned int* __restrict__ flagw,
                  float* __restrict__ t, int e) {
    __shared__ int2 q[QCAP];
    __shared__ int qn;
    const int tid = threadIdx.x;
    if (tid == 0) qn = 0;
    __syncthreads();

    const int4* ed4 = (const int4*)edst;
    const int4* es4 = (const int4*)esrc;
    const int e4 = e >> 2;
    const int g0 = blockIdx.x * 512;      // int4-group base; block covers 2048 edges
#pragma unroll
    for (int u = 0; u < 2; u++) {
        int gi = g0 + u * 256 + tid;
        if (gi < e4) {
            int4 dd = ed4[gi];
            int4 ss = es4[gi];
#pragma unroll
            for (int c = 0; c < 4; c++) {
                int d = (&dd.x)[c];
                if ((flagw[(unsigned)d >> 5] >> (d & 31)) & 1u) {
                    int p = atomicAdd(&qn, 1);
                    if (p < QCAP) q[p] = make_int2((&ss.x)[c], d);
                    else atomicAdd(t + d, dx[(&ss.x)[c]].y);   // overflow fallback
                }
            }
        }
    }
    // tail edges (e % 4) — block 0 handles inline
    if (blockIdx.x == 0) {
        for (int j = (e4 << 2) + tid; j < e; j += 256) {
            int d = edst[j];
            if ((flagw[(unsigned)d >> 5] >> (d & 31)) & 1u) {
                int s = esrc[j];
                atomicAdd(t + d, dx[s].y);
            }
        }
    }
    __syncthreads();
    int m = min(qn, QCAP);
    for (int i = tid; i < m; i += 256) {
        int2 sd = q[i];
        atomicAdd(t + sd.y, dx[sd.x].y);
    }
}

// Pass 4 (channel-parallel): one WAVE per gene. Lane = (channel c 0-15,
// edge-slot 0-3). Pairwise gene_src prefetch: both bucket loads issued
// before the dependent dx/t gathers.
__global__ void k_gene_final(const int* __restrict__ gene_cnt, const int* __restrict__ gene_src,
                             const float* __restrict__ t, const float2* __restrict__ dx,
                             const float* __restrict__ W1, const float* __restrict__ b1,
                             const float* __restrict__ W2, const float* __restrict__ b2,
                             const float* __restrict__ fw1, const float* __restrict__ fb1,
                             const float* __restrict__ fw2, const float* __restrict__ fb2,
                             float* __restrict__ out, int NG, int G) {
    int wid = (blockIdx.x * blockDim.x + threadIdx.x) >> 6;
    int lane = threadIdx.x & 63;
    if (wid >= NG) return;
    int g = wid;
    int graph = g / NHEADS;
    int head = g - graph * NHEADS;
    int node = graph * NODES + GENE0 + head;
    const int c = lane & 15;
    const int slot = lane >> 4;

    int cnt = min(gene_cnt[g], GMAX);     // early scalar load

    float w1r[16], b1r[16], w2c[16];
#pragma unroll
    for (int kk = 0; kk < 16; kk++) {
        w1r[kk] = W1[kk];
        b1r[kk] = b1[kk];
        w2c[kk] = W2[kk * 16 + c];
    }
    float2 dn2 = dx[node];
    float tn = t[node];

    float acc = 0.f;
    const int base = g << 6;
    for (int i = slot; i < cnt; i += 8) {
        int s0 = gene_src[base + i];
        int i1 = i + 4;
        int s1 = (i1 < cnt) ? gene_src[base + i1] : -1;
        // issue both gather sets before consuming
        float2 a2 = dx[s0];
        float ta = t[s0];
        float2 b2v = (s1 >= 0) ? dx[s1] : make_float2(0.f, 0.f);
        float tb = (s1 >= 0) ? t[s1] : 0.f;
        {
            float us = a2.x * ta + a2.x * a2.y;
            float m = 0.f;
#pragma unroll
            for (int kk = 0; kk < 16; kk++)
                m += frelu(us * w1r[kk] + b1r[kk]) * w2c[kk];
            acc += a2.x * m;
        }
        if (s1 >= 0) {
            float us = b2v.x * tb + b2v.x * b2v.y;
            float m = 0.f;
#pragma unroll
            for (int kk = 0; kk < 16; kk++)
                m += frelu(us * w1r[kk] + b1r[kk]) * w2c[kk];
            acc += b2v.x * m;
        }
    }
    acc += __shfl_xor(acc, 16, 64);
    acc += __shfl_xor(acc, 32, 64);

    float dn = dn2.x;
    float un = dn * tn + dn * dn2.y;
    float h2 = 0.f;
#pragma unroll
    for (int kk = 0; kk < 16; kk++)
        h2 += frelu(un * w1r[kk] + b1r[kk]) * w2c[kk];
    float h = frelu(dn * acc + dn * dn * h2 + b2[c]);

    float hv[16];
#pragma unroll
    for (int c2 = 0; c2 < 16; c2++) hv[c2] = __shfl(h, c2, 64);

    int kk = lane & 7;
    float z = fb1[head * 8 + kk];
#pragma unroll
    for (int c2 = 0; c2 < 16; c2++) z += hv[c2] * fw1[head * 128 + c2 * 8 + kk];
    float term = frelu(z) * fw2[head * 8 + kk];
    term += __shfl_xor(term, 1, 64);
    term += __shfl_xor(term, 2, 64);
    term += __shfl_xor(term, 4, 64);
    if (lane == 0) out[head * G + graph] = fb2[head] + term;
}

extern "C" void kernel_launch(void* const* d_in, const int* in_sizes, int n_in,
                              void* d_out, int out_size, void* d_ws, size_t ws_size,
                              hipStream_t stream) {
    const float* x   = (const float*)d_in[0];
    const int*   ei  = (const int*)d_in[1];
    const float* W1  = (const float*)d_in[3];
    const float* b1  = (const float*)d_in[4];
    const float* W2  = (const float*)d_in[5];
    const float* b2  = (const float*)d_in[6];
    const float* fw1 = (const float*)d_in[7];
    const float* fb1 = (const float*)d_in[8];
    const float* fw2 = (const float*)d_in[9];
    const float* fb2 = (const float*)d_in[10];

    int n = in_sizes[0];
    int e = in_sizes[1] / 2;
    int G = in_sizes[2] / NHEADS;
    int NG = G * NHEADS;
    const int* esrc = ei;
    const int* edst = ei + e;

    char* ws = (char*)d_ws;
    size_t off = 0;
    auto alloc = [&](size_t bytes) {
        char* p = ws + off;
        off += (bytes + 255) & ~(size_t)255;
        return p;
    };
    // zero-init region: gene counters + flag bitmask
    int*   gene_cnt      = (int*)alloc((size_t)NG * 4);
    unsigned int* flagw  = (unsigned int*)alloc((size_t)((n + 31) / 32) * 4);
    size_t zero_bytes    = off;
    // written-before-read region
    int*    gene_src     = (int*)alloc((size_t)NG * GMAX * 4);
    float*  t            = (float*)alloc((size_t)n * 4);       // zeroed by k_reduce
    float2* dx           = (float2*)alloc((size_t)n * 8);      // {dinv, dinv*x}
    size_t fixed         = off;

    int R = (n + HBINS - 1) / HBINS;                  // 6 for n=732160
    size_t per_copy = (size_t)R * HWORDS * 4;         // 384 KB per chunk
    int K = 80;                                       // mult of 8; 480 blocks ~ 512 slots
    if (fixed + (size_t)K * per_copy > ws_size) {
        size_t avail = (ws_size > fixed) ? (ws_size - fixed) : 0;
        int kfit = (int)(avail / per_copy);
        if (kfit >= 8) kfit &= ~7;
        K = kfit < 1 ? 1 : (kfit < K ? kfit : K);
    }
    unsigned int* copies = (unsigned int*)alloc((size_t)K * per_copy);
    (void)n_in; (void)out_size;

    hipMemsetAsync(d_ws, 0, zero_bytes, stream);

    const int B = 256;
    k_hist<<<K * R, BHIST, 0, stream>>>(esrc, edst, copies, gene_cnt, gene_src,
                                        flagw, e, K, R);
    int Wtot = R * HWORDS;
    k_reduce<<<(Wtot + B - 1) / B, B, 0, stream>>>(copies, x, dx, t, flagw, n, K, Wtot);
    int nblk = ((e >> 2) + 511) / 512;                // 2048 edges per block
    k_l1_scatter<<<nblk, 256, 0, stream>>>(esrc, edst, dx, flagw, t, e);
    int waves_blocks = (NG * 64 + B - 1) / B;
    k_gene_final<<<waves_blocks, B, 0, stream>>>(gene_cnt, gene_src, t, dx,
                                                 W1, b1, W2, b2,
                                                 fw1, fb1, fw2, fb2,
                                                 (float*)d_out, NG, G);
}

// Round 13
// 170.721 us; speedup vs baseline: 3.8170x; 1.0096x over previous
//
#include <hip/hip_runtime.h>

#define NODES 1430
#define GENE0 1421
#define NHEADS 9
#define HBINS 131072         // bins per block; 4-bit counts, 8 per u32
#define HWORDS (HBINS / 8)   // 16384 u32 words = 64 KB LDS (gfx9 per-WG max)
#define BHIST 1024           // 16 waves/block; 2 blocks/CU thread-cap
#define GMAX 64              // max bucketed in-edges per gene (Poisson(8) tail ~0)
#define QCAP 1024            // hit-queue capacity (expected ~115/block at 2048 edges)

__device__ __forceinline__ float frelu(float v) { return v > 0.f ? v : 0.f; }

// Pass 1: privatized LDS histogram (4-bit packed) of in-degree.
// 1-D grid of K*R blocks, XCD-swizzled (confirmed R8: FETCH 71->20 MB).
// 8 independent load streams (R6's 8-stream test was confounded by the
// transposed grid; retried here under the working swizzle).
__global__ __launch_bounds__(BHIST, 4)
void k_hist(const int* __restrict__ esrc, const int* __restrict__ edst,
            unsigned int* __restrict__ copies,      // [K][R*HWORDS]
            int* __restrict__ gene_cnt, int* __restrict__ gene_src,
            unsigned int* __restrict__ flagw,
            int e, int K, int R) {
    __shared__ unsigned int lds[HWORDS];
    int id = blockIdx.x;
    int k, r;
    if ((K & 7) == 0) {
        int xcd = id & 7;
        int slot = id >> 3;
        int cin = slot / R;
        k = xcd * (K >> 3) + cin;
        r = slot - cin * R;
    } else {
        k = id / R;
        r = id - k * R;
    }
    const int tid = threadIdx.x;
    {
        uint4* l4 = (uint4*)lds;
        for (int w = tid; w < HWORDS / 4; w += BHIST) l4[w] = make_uint4(0, 0, 0, 0);
    }
    __syncthreads();

    const unsigned int lo = (unsigned int)r * HBINS;
    const int e4 = e >> 2;
    const int Q = (e4 + K - 1) / K;
    const int beg = k * Q;
    const int end = min(beg + Q, e4);
    const int4* ed4 = (const int4*)edst;
    const int len = (end > beg) ? (end - beg) : 0;
    const int eighth = len >> 3;

    auto proc = [&](int4 d4) {
#pragma unroll
        for (int c = 0; c < 4; c++) {
            unsigned int d = (unsigned int)((&d4.x)[c]);
            unsigned int rel = d - lo;
            if (rel < HBINS)
                atomicAdd(&lds[rel >> 3], 1u << ((rel & 7u) * 4u));
        }
    };

    // eight independent streams -> 8 int4 loads in flight per wave
    for (int i = tid; i < eighth; i += BHIST) {
        int j0 = beg + i;
        int4 v0 = ed4[j0];
        int4 v1 = ed4[j0 + eighth];
        int4 v2 = ed4[j0 + 2 * eighth];
        int4 v3 = ed4[j0 + 3 * eighth];
        int4 v4 = ed4[j0 + 4 * eighth];
        int4 v5 = ed4[j0 + 5 * eighth];
        int4 v6 = ed4[j0 + 6 * eighth];
        int4 v7 = ed4[j0 + 7 * eighth];
        proc(v0); proc(v1); proc(v2); proc(v3);
        proc(v4); proc(v5); proc(v6); proc(v7);
    }
    for (int i = (eighth << 3) + tid; i < len; i += BHIST) {
        proc(ed4[beg + i]);
    }

    // gene-scan: this block's sub-slice of the chunk (edges are L2-hot).
    {
        int sbeg = beg + (int)(((long long)len * r) / R);
        int send = beg + (int)(((long long)len * (r + 1)) / R);
        for (int j = sbeg + tid; j < send; j += BHIST) {
            int4 d4 = ed4[j];
#pragma unroll
            for (int c = 0; c < 4; c++) {
                unsigned int d = (unsigned int)((&d4.x)[c]);
                unsigned int graph = d / NODES;
                unsigned int pos = d - graph * NODES;
                if (pos >= GENE0) {
                    int s = esrc[4 * j + c];
                    atomicOr(&flagw[(unsigned)s >> 5], 1u << (s & 31));
                    int g = (int)(graph * NHEADS + (pos - GENE0));
                    int p = atomicAdd(gene_cnt + g, 1);
                    if (p < GMAX) gene_src[(g << 6) + p] = s;
                }
            }
        }
    }

    // tail edges (e % 4)
    if (k == 0) {
        for (int j = (e4 << 2) + tid; j < e; j += BHIST) {
            unsigned int d = (unsigned int)edst[j];
            unsigned int rel = d - lo;
            if (rel < HBINS)
                atomicAdd(&lds[rel >> 3], 1u << ((rel & 7u) * 4u));
            if (r == 0) {
                unsigned int graph = d / NODES;
                unsigned int pos = d - graph * NODES;
                if (pos >= GENE0) {
                    int s = esrc[j];
                    atomicOr(&flagw[(unsigned)s >> 5], 1u << (s & 31));
                    int g = (int)(graph * NHEADS + (pos - GENE0));
                    int p = atomicAdd(gene_cnt + g, 1);
                    if (p < GMAX) gene_src[(g << 6) + p] = s;
                }
            }
        }
    }
    __syncthreads();
    uint4* dst4 = (uint4*)(copies + ((size_t)k * R + r) * HWORDS);
    const uint4* l4 = (const uint4*)lds;
    for (int w = tid; w < HWORDS / 4; w += BHIST) dst4[w] = l4[w];
}

// Pass 2: sum K nibble-histograms (SWAR, 8 independent streams). Writes
// dx[i] = {dinv, dinv*x}, zeroes t, sets gene-node flag bits.
__global__ void k_reduce(const unsigned int* __restrict__ copies,
                         const float* __restrict__ x,
                         float2* __restrict__ dx, float* __restrict__ t,
                         unsigned int* __restrict__ flagw,
                         int n, int K, int Wtot) {
    int w = blockIdx.x * blockDim.x + threadIdx.x;
    if (w >= Wtot) return;
    const unsigned int M = 0x0F0F0F0Fu;
    unsigned int ev[8] = {0, 0, 0, 0, 0, 0, 0, 0};
    unsigned int od[8] = {0, 0, 0, 0, 0, 0, 0, 0};
    int k = 0;
    for (; k + 8 <= K; k += 8) {
#pragma unroll
        for (int s = 0; s < 8; s++) {
            unsigned int u = copies[(size_t)(k + s) * Wtot + w];
            ev[s] += u & M; od[s] += (u >> 4) & M;
        }
    }
    for (; k < K; k++) {
        unsigned int u = copies[(size_t)k * Wtot + w];
        ev[0] += u & M; od[0] += (u >> 4) & M;
    }
    unsigned int evn = ((ev[0] + ev[1]) + (ev[2] + ev[3])) + ((ev[4] + ev[5]) + (ev[6] + ev[7]));
    unsigned int odd = ((od[0] + od[1]) + (od[2] + od[3])) + ((od[4] + od[5]) + (od[6] + od[7]));
    int i0 = w << 3;
    float v[8];
#pragma unroll
    for (int b = 0; b < 4; b++) {
        v[2 * b]     = (float)((evn >> (8 * b)) & 0xFFu);
        v[2 * b + 1] = (float)((odd >> (8 * b)) & 0xFFu);
    }
#pragma unroll
    for (int b = 0; b < 8; b++) v[b] = rsqrtf(v[b] + 1.f);
    float4 z4 = {0.f, 0.f, 0.f, 0.f};
    if (i0 + 7 < n) {
        float4 xa = *(const float4*)(x + i0);
        float4 xb = *(const float4*)(x + i0 + 4);
        float4 p0 = {v[0], v[0] * xa.x, v[1], v[1] * xa.y};
        float4 p1 = {v[2], v[2] * xa.z, v[3], v[3] * xa.w};
        float4 p2 = {v[4], v[4] * xb.x, v[5], v[5] * xb.y};
        float4 p3 = {v[6], v[6] * xb.z, v[7], v[7] * xb.w};
        float4* dst = (float4*)(dx + i0);
        dst[0] = p0; dst[1] = p1; dst[2] = p2; dst[3] = p3;
        *(float4*)(t + i0) = z4;
        *(float4*)(t + i0 + 4) = z4;
    } else {
        for (int b = 0; b < 8; b++)
            if (i0 + b < n) {
                float xv = x[i0 + b];
                dx[i0 + b] = make_float2(v[b], v[b] * xv);
                t[i0 + b] = 0.f;
            }
    }
#pragma unroll
    for (int b = 0; b < 8; b++) {
        int i = i0 + b;
        if (i < n) {
            unsigned int graph = (unsigned int)i / NODES;
            unsigned int pos = (unsigned int)i - graph * NODES;
            if (pos >= GENE0) atomicOr(&flagw[(unsigned)i >> 5], 1u << (i & 31));
        }
    }
}

// Pass 3: layer-1 scatter into flagged dst only (~5.6% of edges).
// 2048 edges/block; LDS hit-queue decouples scan from atomic drain.
__global__ __launch_bounds__(256, 8)
void k_l1_scatter(const int* __restrict__ esrc, const int* __restrict__ edst,
                  const float2* __restrict__ dx,
                  const unsigned int* __restrict__ flagw,
                  float* __restrict__ t, int e) {
    __shared__ int2 q[QCAP];
    __shared__ int qn;
    const int tid = threadIdx.x;
    if (tid == 0) qn = 0;
    __syncthreads();

    const int4* ed4 = (const int4*)edst;
    const int4* es4 = (const int4*)esrc;
    const int e4 = e >> 2;
    const int g0 = blockIdx.x * 512;
#pragma unroll
    for (int u = 0; u < 2; u++) {
        int gi = g0 + u * 256 + tid;
        if (gi < e4) {
            int4 dd = ed4[gi];
            int4 ss = es4[gi];
#pragma unroll
            for (int c = 0; c < 4; c++) {
                int d = (&dd.x)[c];
                if ((flagw[(unsigned)d >> 5] >> (d & 31)) & 1u) {
                    int p = atomicAdd(&qn, 1);
                    if (p < QCAP) q[p] = make_int2((&ss.x)[c], d);
                    else atomicAdd(t + d, dx[(&ss.x)[c]].y);
                }
            }
        }
    }
    if (blockIdx.x == 0) {
        for (int j = (e4 << 2) + tid; j < e; j += 256) {
            int d = edst[j];
            if ((flagw[(unsigned)d >> 5] >> (d & 31)) & 1u) {
                int s = esrc[j];
                atomicAdd(t + d, dx[s].y);
            }
        }
    }
    __syncthreads();
    int m = min(qn, QCAP);
    for (int i = tid; i < m; i += 256) {
        int2 sd = q[i];
        atomicAdd(t + sd.y, dx[sd.x].y);
    }
}

// Pass 4 (channel-parallel): one WAVE per gene. Lane = (channel c 0-15,
// edge-slot 0-3). Pairwise gene_src prefetch.
__global__ void k_gene_final(const int* __restrict__ gene_cnt, const int* __restrict__ gene_src,
                             const float* __restrict__ t, const float2* __restrict__ dx,
                             const float* __restrict__ W1, const float* __restrict__ b1,
                             const float* __restrict__ W2, const float* __restrict__ b2,
                             const float* __restrict__ fw1, const float* __restrict__ fb1,
                             const float* __restrict__ fw2, const float* __restrict__ fb2,
                             float* __restrict__ out, int NG, int G) {
    int wid = (blockIdx.x * blockDim.x + threadIdx.x) >> 6;
    int lane = threadIdx.x & 63;
    if (wid >= NG) return;
    int g = wid;
    int graph = g / NHEADS;
    int head = g - graph * NHEADS;
    int node = graph * NODES + GENE0 + head;
    const int c = lane & 15;
    const int slot = lane >> 4;

    int cnt = min(gene_cnt[g], GMAX);

    float w1r[16], b1r[16], w2c[16];
#pragma unroll
    for (int kk = 0; kk < 16; kk++) {
        w1r[kk] = W1[kk];
        b1r[kk] = b1[kk];
        w2c[kk] = W2[kk * 16 + c];
    }
    float2 dn2 = dx[node];
    float tn = t[node];

    float acc = 0.f;
    const int base = g << 6;
    for (int i = slot; i < cnt; i += 8) {
        int s0 = gene_src[base + i];
        int i1 = i + 4;
        int s1 = (i1 < cnt) ? gene_src[base + i1] : -1;
        float2 a2 = dx[s0];
        float ta = t[s0];
        float2 b2v = (s1 >= 0) ? dx[s1] : make_float2(0.f, 0.f);
        float tb = (s1 >= 0) ? t[s1] : 0.f;
        {
            float us = a2.x * ta + a2.x * a2.y;
            float m = 0.f;
#pragma unroll
            for (int kk = 0; kk < 16; kk++)
                m += frelu(us * w1r[kk] + b1r[kk]) * w2c[kk];
            acc += a2.x * m;
        }
        if (s1 >= 0) {
            float us = b2v.x * tb + b2v.x * b2v.y;
            float m = 0.f;
#pragma unroll
            for (int kk = 0; kk < 16; kk++)
                m += frelu(us * w1r[kk] + b1r[kk]) * w2c[kk];
            acc += b2v.x * m;
        }
    }
    acc += __shfl_xor(acc, 16, 64);
    acc += __shfl_xor(acc, 32, 64);

    float dn = dn2.x;
    float un = dn * tn + dn * dn2.y;
    float h2 = 0.f;
#pragma unroll
    for (int kk = 0; kk < 16; kk++)
        h2 += frelu(un * w1r[kk] + b1r[kk]) * w2c[kk];
    float h = frelu(dn * acc + dn * dn * h2 + b2[c]);

    float hv[16];
#pragma unroll
    for (int c2 = 0; c2 < 16; c2++) hv[c2] = __shfl(h, c2, 64);

    int kk = lane & 7;
    float z = fb1[head * 8 + kk];
#pragma unroll
    for (int c2 = 0; c2 < 16; c2++) z += hv[c2] * fw1[head * 128 + c2 * 8 + kk];
    float term = frelu(z) * fw2[head * 8 + kk];
    term += __shfl_xor(term, 1, 64);
    term += __shfl_xor(term, 2, 64);
    term += __shfl_xor(term, 4, 64);
    if (lane == 0) out[head * G + graph] = fb2[head] + term;
}

extern "C" void kernel_launch(void* const* d_in, const int* in_sizes, int n_in,
                              void* d_out, int out_size, void* d_ws, size_t ws_size,
                              hipStream_t stream) {
    const float* x   = (const float*)d_in[0];
    const int*   ei  = (const int*)d_in[1];
    const float* W1  = (const float*)d_in[3];
    const float* b1  = (const float*)d_in[4];
    const float* W2  = (const float*)d_in[5];
    const float* b2  = (const float*)d_in[6];
    const float* fw1 = (const float*)d_in[7];
    const float* fb1 = (const float*)d_in[8];
    const float* fw2 = (const float*)d_in[9];
    const float* fb2 = (const float*)d_in[10];

    int n = in_sizes[0];
    int e = in_sizes[1] / 2;
    int G = in_sizes[2] / NHEADS;
    int NG = G * NHEADS;
    const int* esrc = ei;
    const int* edst = ei + e;

    char* ws = (char*)d_ws;
    size_t off = 0;
    auto alloc = [&](size_t bytes) {
        char* p = ws + off;
        off += (bytes + 255) & ~(size_t)255;
        return p;
    };
    int*   gene_cnt      = (int*)alloc((size_t)NG * 4);
    unsigned int* flagw  = (unsigned int*)alloc((size_t)((n + 31) / 32) * 4);
    size_t zero_bytes    = off;
    int*    gene_src     = (int*)alloc((size_t)NG * GMAX * 4);
    float*  t            = (float*)alloc((size_t)n * 4);       // zeroed by k_reduce
    float2* dx           = (float2*)alloc((size_t)n * 8);      // {dinv, dinv*x}
    size_t fixed         = off;

    int R = (n + HBINS - 1) / HBINS;                  // 6 for n=732160
    size_t per_copy = (size_t)R * HWORDS * 4;         // 384 KB per chunk
    int K = 80;                                       // mult of 8; 480 blocks ~ 512 slots
    if (fixed + (size_t)K * per_copy > ws_size) {
        size_t avail = (ws_size > fixed) ? (ws_size - fixed) : 0;
        int kfit = (int)(avail / per_copy);
        if (kfit >= 8) kfit &= ~7;
        K = kfit < 1 ? 1 : (kfit < K ? kfit : K);
    }
    unsigned int* copies = (unsigned int*)alloc((size_t)K * per_copy);
    (void)n_in; (void)out_size;

    hipMemsetAsync(d_ws, 0, zero_bytes, stream);

    const int B = 256;
    k_hist<<<K * R, BHIST, 0, stream>>>(esrc, edst, copies, gene_cnt, gene_src,
                                        flagw, e, K, R);
    int Wtot = R * HWORDS;
    k_reduce<<<(Wtot + B - 1) / B, B, 0, stream>>>(copies, x, dx, t, flagw, n, K, Wtot);
    int nblk = ((e >> 2) + 511) / 512;                // 2048 edges per block
    k_l1_scatter<<<nblk, 256, 0, stream>>>(esrc, edst, dx, flagw, t, e);
    int waves_blocks = (NG * 64 + B - 1) / B;
    k_gene_final<<<waves_blocks, B, 0, stream>>>(gene_cnt, gene_src, t, dx,
                                                 W1, b1, W2, b2,
                                                 fw1, fb1, fw2, fb2,
                                                 (float*)d_out, NG, G);
}